// Round 1
// baseline (319.754 us; speedup 1.0000x reference)
//
#include <hip/hip_runtime.h>
#include <stdint.h>

// ---- problem constants ----
#define BB 2
#define TT 2048
#define EE 1024
#define HH 16
#define DD 64
#define NHH 1024
#define BT 4096  // BB*TT

typedef unsigned short u16_t;
typedef __bf16 bf16_t;
typedef bf16_t bf16x8 __attribute__((ext_vector_type(8)));
typedef float f32x4 __attribute__((ext_vector_type(4)));

__device__ __forceinline__ u16_t f2bf(float f) {
  union { float f; uint32_t u; } v; v.f = f;
  return (u16_t)((v.u + 0x7fffu + ((v.u >> 16) & 1u)) >> 16);
}

__device__ __forceinline__ void gl_lds16(const u16_t* g, u16_t* l) {
  __builtin_amdgcn_global_load_lds(
      (const __attribute__((address_space(1))) uint32_t*)g,
      (__attribute__((address_space(3))) uint32_t*)l, 16, 0, 0);
}

// ---- fp32 -> bf16 convert (vectorized) ----
__global__ __launch_bounds__(256) void cvt_f32_bf16(const float* __restrict__ in,
                                                    u16_t* __restrict__ out, int n4) {
  int i = blockIdx.x * 256 + threadIdx.x;
  if (i < n4) {
    float4 v = ((const float4*)in)[i];
    ushort4 o;
    o.x = f2bf(v.x); o.y = f2bf(v.y); o.z = f2bf(v.z); o.w = f2bf(v.w);
    ((ushort4*)out)[i] = o;
  }
}

// ---- GEMM: C[m][n] = sum_k A[m][k] * W[n][k], A,W bf16, C fp32 or bf16 ----
// 128x128 tile, BK=64, 4 waves (2x2), 16x16x32 MFMA, global_load_lds staging,
// XOR chunk swizzle (source-side) so frag ds_read_b128 is conflict-free.
template <int OUT_BF16>
__global__ __launch_bounds__(256, 2) void gemm_bt(const u16_t* __restrict__ A,
                                                  const u16_t* __restrict__ W,
                                                  void* __restrict__ Cp,
                                                  int M, int N, int K) {
  __shared__ __align__(16) u16_t As[128 * 64];
  __shared__ __align__(16) u16_t Bs[128 * 64];
  const int tid = threadIdx.x;
  const int lane = tid & 63;
  const int w = tid >> 6;
  const int wm = w >> 1, wn = w & 1;
  const int mt = blockIdx.y, nt = blockIdx.x;
  const int l15 = lane & 15, l4 = lane >> 4;

  f32x4 acc[4][4] = {};
  const int nk = K >> 6;
  for (int ks = 0; ks < nk; ++ks) {
    const int k0 = ks << 6;
#pragma unroll
    for (int i = 0; i < 4; ++i) {
      int ci = i * 256 + w * 64 + lane;  // 0..1023 chunk of 16B
      int row = ci >> 3, c8 = ci & 7;
      int c8s = c8 ^ (row & 7);
      gl_lds16(A + (size_t)(mt * 128 + row) * K + k0 + c8s * 8,
               &As[(i * 256 + w * 64) * 8]);
      gl_lds16(W + (size_t)(nt * 128 + row) * K + k0 + c8s * 8,
               &Bs[(i * 256 + w * 64) * 8]);
    }
    __syncthreads();
#pragma unroll
    for (int kt = 0; kt < 2; ++kt) {
      bf16x8 af[4], bfr[4];
#pragma unroll
      for (int m = 0; m < 4; ++m) {
        int r = wm * 64 + m * 16 + l15;
        af[m] = *(const bf16x8*)&As[r * 64 + ((kt * 4 + l4) ^ (r & 7)) * 8];
      }
#pragma unroll
      for (int n = 0; n < 4; ++n) {
        int r = wn * 64 + n * 16 + l15;
        bfr[n] = *(const bf16x8*)&Bs[r * 64 + ((kt * 4 + l4) ^ (r & 7)) * 8];
      }
#pragma unroll
      for (int m = 0; m < 4; ++m)
#pragma unroll
        for (int n = 0; n < 4; ++n)
          acc[m][n] = __builtin_amdgcn_mfma_f32_16x16x32_bf16(af[m], bfr[n], acc[m][n], 0, 0, 0);
    }
    __syncthreads();
  }
  // epilogue: C/D layout col = lane&15, row = (lane>>4)*4 + reg
#pragma unroll
  for (int m = 0; m < 4; ++m)
#pragma unroll
    for (int n = 0; n < 4; ++n)
#pragma unroll
      for (int r = 0; r < 4; ++r) {
        int row = mt * 128 + wm * 64 + m * 16 + l4 * 4 + r;
        int col = nt * 128 + wn * 64 + n * 16 + l15;
        if (OUT_BF16) {
          ((u16_t*)Cp)[(size_t)row * N + col] = f2bf(acc[m][n][r]);
        } else {
          ((float*)Cp)[(size_t)row * N + col] = acc[m][n][r];
        }
      }
}

// ---- row LayerNorm over NH=1024, fp32 in -> bf16 out ----
__global__ __launch_bounds__(256) void ln_rows(const float* __restrict__ X,
                                               const float* __restrict__ scale,
                                               const float* __restrict__ bias,
                                               u16_t* __restrict__ Y) {
  int row = blockIdx.x;
  int tid = threadIdx.x;
  const float* x = X + (size_t)row * NHH;
  float4 v = ((const float4*)x)[tid];
  float s = v.x + v.y + v.z + v.w;
  float sq = v.x * v.x + v.y * v.y + v.z * v.z + v.w * v.w;
#pragma unroll
  for (int m = 1; m < 64; m <<= 1) {
    s += __shfl_xor(s, m);
    sq += __shfl_xor(sq, m);
  }
  __shared__ float ss[4], ssq[4];
  int w = tid >> 6;
  if ((tid & 63) == 0) { ss[w] = s; ssq[w] = sq; }
  __syncthreads();
  s = ss[0] + ss[1] + ss[2] + ss[3];
  sq = ssq[0] + ssq[1] + ssq[2] + ssq[3];
  float mean = s * (1.0f / 1024.0f);
  float var = sq * (1.0f / 1024.0f) - mean * mean;
  float rstd = rsqrtf(var + 1e-5f);
  float4 sc = ((const float4*)scale)[tid];
  float4 bi = ((const float4*)bias)[tid];
  ushort4 o;
  o.x = f2bf((v.x - mean) * rstd * sc.x + bi.x);
  o.y = f2bf((v.y - mean) * rstd * sc.y + bi.y);
  o.z = f2bf((v.z - mean) * rstd * sc.z + bi.z);
  o.w = f2bf((v.w - mean) * rstd * sc.w + bi.w);
  ((ushort4*)Y)[(size_t)row * 256 + tid] = o;
}

// ---- V [BT, NH] -> Vt [B,H,D,T] ----
__global__ __launch_bounds__(256) void transpose_v(const u16_t* __restrict__ V,
                                                   u16_t* __restrict__ Vt) {
  __shared__ u16_t tile[64][72];
  int tt = blockIdx.x, bh = blockIdx.y;
  int b = bh >> 4, h = bh & 15;
  int tid = threadIdx.x;
#pragma unroll
  for (int i = 0; i < 4; ++i) {
    int idx = i * 256 + tid;          // ushort4 units, 1024 total
    int t = idx >> 4, c4 = idx & 15;  // 16 ushort4 per 64-col row
    ushort4 v = *(const ushort4*)&V[(size_t)(b * TT + tt * 64 + t) * NHH + h * 64 + c4 * 4];
    *(ushort4*)&tile[t][c4 * 4] = v;
  }
  __syncthreads();
#pragma unroll
  for (int i = 0; i < 4; ++i) {
    int idx = i * 256 + tid;
    int d = idx >> 4, c4 = idx & 15;
    ushort4 o;
    o.x = tile[c4 * 4 + 0][d];
    o.y = tile[c4 * 4 + 1][d];
    o.z = tile[c4 * 4 + 2][d];
    o.w = tile[c4 * 4 + 3][d];
    *(ushort4*)&Vt[((size_t)bh * 64 + d) * TT + tt * 64 + c4 * 4] = o;
  }
}

// ---- causal flash attention: Q,K [BT,NH] bf16 (post-LN), Vt [B,H,D,T] bf16 ----
// grid (bh=32, qt=32), 4 waves/block, each wave owns 16 q-rows; kv tiles of 64.
__global__ __launch_bounds__(256, 2) void attn_fwd(const u16_t* __restrict__ Q,
                                                   const u16_t* __restrict__ K,
                                                   const u16_t* __restrict__ Vt,
                                                   u16_t* __restrict__ O) {
  __shared__ __align__(16) u16_t Ks[64 * 64];
  __shared__ __align__(16) u16_t Vs[64 * 64];
  __shared__ __align__(16) u16_t Ps[4][16 * 72];
  int bh = blockIdx.x, qt = blockIdx.y;
  int b = bh >> 4, h = bh & 15;
  int tid = threadIdx.x, lane = tid & 63, w = tid >> 6;
  int l15 = lane & 15, l4 = lane >> 4;

  const float SCALE = 0.125f * 1.44269504f;  // 1/sqrt(D) * log2(e), exp2 domain

  // Q fragments (A-layout: row = lane&15, k = (lane>>4)*8 + i)
  bf16x8 qf[2];
#pragma unroll
  for (int kt = 0; kt < 2; ++kt)
    qf[kt] = *(const bf16x8*)&Q[(size_t)(b * TT + qt * 64 + w * 16 + l15) * NHH +
                                h * 64 + kt * 32 + l4 * 8];

  f32x4 accO[4] = {};
  float mrow[4], lrow[4];
#pragma unroll
  for (int r = 0; r < 4; ++r) { mrow[r] = -1e30f; lrow[r] = 0.f; }
  const int q_lane_row = qt * 64 + w * 16 + l4 * 4;  // + r : C-layout rows

  for (int j = 0; j <= qt; ++j) {
    // stage K tile [64 kv][64 d] and Vt tile [64 d][64 kv], source-side XOR swizzle
#pragma unroll
    for (int i = 0; i < 2; ++i) {
      int ci = i * 256 + w * 64 + lane;  // 0..511
      int row = ci >> 3, c8 = ci & 7;
      int c8s = c8 ^ (row & 7);
      gl_lds16(K + (size_t)(b * TT + j * 64 + row) * NHH + h * 64 + c8s * 8,
               &Ks[(i * 256 + w * 64) * 8]);
      gl_lds16(Vt + ((size_t)bh * 64 + row) * TT + j * 64 + c8s * 8,
               &Vs[(i * 256 + w * 64) * 8]);
    }
    __syncthreads();

    // S = Q K^T  (4 kv-subtiles of 16)
    f32x4 s[4];
#pragma unroll
    for (int n = 0; n < 4; ++n) {
      s[n] = (f32x4){0.f, 0.f, 0.f, 0.f};
#pragma unroll
      for (int kt = 0; kt < 2; ++kt) {
        int r = n * 16 + l15;
        bf16x8 kf = *(const bf16x8*)&Ks[r * 64 + ((kt * 4 + l4) ^ (r & 7)) * 8];
        s[n] = __builtin_amdgcn_mfma_f32_16x16x32_bf16(qf[kt], kf, s[n], 0, 0, 0);
      }
    }
    // scale + causal mask (diagonal tile only)
    bool diag = (j == qt);
#pragma unroll
    for (int n = 0; n < 4; ++n)
#pragma unroll
      for (int r = 0; r < 4; ++r) {
        float sv = s[n][r] * SCALE;
        if (diag && (j * 64 + n * 16 + l15) > (q_lane_row + r)) sv = -1e30f;
        s[n][r] = sv;
      }
    // online softmax (rows = l4*4+r, reduce over the 16 l15 lanes)
    float tmax[4], mnew[4], scl[4], tsum[4];
#pragma unroll
    for (int r = 0; r < 4; ++r)
      tmax[r] = fmaxf(fmaxf(s[0][r], s[1][r]), fmaxf(s[2][r], s[3][r]));
#pragma unroll
    for (int msk = 1; msk < 16; msk <<= 1)
#pragma unroll
      for (int r = 0; r < 4; ++r) tmax[r] = fmaxf(tmax[r], __shfl_xor(tmax[r], msk));
#pragma unroll
    for (int r = 0; r < 4; ++r) {
      mnew[r] = fmaxf(mrow[r], tmax[r]);
      scl[r] = exp2f(mrow[r] - mnew[r]);
      tsum[r] = 0.f;
    }
#pragma unroll
    for (int n = 0; n < 4; ++n)
#pragma unroll
      for (int r = 0; r < 4; ++r) {
        float p = exp2f(s[n][r] - mnew[r]);
        s[n][r] = p;
        tsum[r] += p;
      }
#pragma unroll
    for (int msk = 1; msk < 16; msk <<= 1)
#pragma unroll
      for (int r = 0; r < 4; ++r) tsum[r] += __shfl_xor(tsum[r], msk);
#pragma unroll
    for (int r = 0; r < 4; ++r) {
      lrow[r] = lrow[r] * scl[r] + tsum[r];
      mrow[r] = mnew[r];
    }
#pragma unroll
    for (int dn = 0; dn < 4; ++dn)
#pragma unroll
      for (int r = 0; r < 4; ++r) accO[dn][r] *= scl[r];

    // P -> per-wave LDS (bf16, rows padded to 72 elems), then PV
    u16_t* pw = &Ps[w][0];
#pragma unroll
    for (int n = 0; n < 4; ++n)
#pragma unroll
      for (int r = 0; r < 4; ++r)
        pw[(l4 * 4 + r) * 72 + n * 16 + l15] = f2bf(s[n][r]);
#pragma unroll
    for (int kt = 0; kt < 2; ++kt) {
      bf16x8 pf = *(const bf16x8*)&pw[l15 * 72 + kt * 32 + l4 * 8];
#pragma unroll
      for (int dn = 0; dn < 4; ++dn) {
        int r = dn * 16 + l15;
        bf16x8 vf = *(const bf16x8*)&Vs[r * 64 + ((kt * 4 + l4) ^ (r & 7)) * 8];
        accO[dn] = __builtin_amdgcn_mfma_f32_16x16x32_bf16(pf, vf, accO[dn], 0, 0, 0);
      }
    }
    __syncthreads();
  }
  // epilogue
  float rinv[4];
#pragma unroll
  for (int r = 0; r < 4; ++r) rinv[r] = 1.0f / lrow[r];
#pragma unroll
  for (int dn = 0; dn < 4; ++dn)
#pragma unroll
    for (int r = 0; r < 4; ++r) {
      int row = b * TT + q_lane_row + r;
      int col = h * 64 + dn * 16 + l15;
      O[(size_t)row * NHH + col] = f2bf(accO[dn][r] * rinv[r]);
    }
}

// ---- launch ----
extern "C" void kernel_launch(void* const* d_in, const int* in_sizes, int n_in,
                              void* d_out, int out_size, void* d_ws, size_t ws_size,
                              hipStream_t stream) {
  const float* inq = (const float*)d_in[0];
  const float* inkv = (const float*)d_in[1];
  // d_in[2] = mask (causal by construction; hard-coded)
  const float* wq = (const float*)d_in[3];
  const float* wk = (const float*)d_in[4];
  const float* wv = (const float*)d_in[5];
  const float* wo = (const float*)d_in[6];
  const float* qs = (const float*)d_in[7];
  const float* qb = (const float*)d_in[8];
  const float* kls = (const float*)d_in[9];
  const float* klb = (const float*)d_in[10];
  float* out = (float*)d_out;

  uint8_t* ws = (uint8_t*)d_ws;
  const size_t SZ_X = (size_t)BT * NHH * 2;   // 8 MiB bf16
  const size_t SZ_W = (size_t)NHH * EE * 2;   // 2 MiB bf16
  const size_t SZ_F = (size_t)BT * NHH * 4;   // 16 MiB fp32
  u16_t* Xq   = (u16_t*)(ws);
  u16_t* Xkv  = (u16_t*)(ws + SZ_X);
  u16_t* Wq   = (u16_t*)(ws + 2 * SZ_X);
  u16_t* Wk   = (u16_t*)(ws + 2 * SZ_X + SZ_W);
  u16_t* Wv   = (u16_t*)(ws + 2 * SZ_X + 2 * SZ_W);
  u16_t* Wo   = (u16_t*)(ws + 2 * SZ_X + 3 * SZ_W);
  float* Qraw = (float*)(ws + 2 * SZ_X + 4 * SZ_W);
  float* Kraw = (float*)(ws + 2 * SZ_X + 4 * SZ_W + SZ_F);
  u16_t* Qln  = (u16_t*)(ws + 2 * SZ_X + 4 * SZ_W + 2 * SZ_F);
  u16_t* Kln  = (u16_t*)(ws + 3 * SZ_X + 4 * SZ_W + 2 * SZ_F);
  u16_t* Vb   = (u16_t*)(ws + 4 * SZ_X + 4 * SZ_W + 2 * SZ_F);
  u16_t* Vt   = (u16_t*)(ws + 5 * SZ_X + 4 * SZ_W + 2 * SZ_F);
  u16_t* AOut = (u16_t*)(ws + 6 * SZ_X + 4 * SZ_W + 2 * SZ_F);

  const int n4x = BT * NHH / 4;  // 1048576
  const int n4w = NHH * EE / 4;  // 262144
  cvt_f32_bf16<<<n4x / 256, 256, 0, stream>>>(inq, Xq, n4x);
  cvt_f32_bf16<<<n4x / 256, 256, 0, stream>>>(inkv, Xkv, n4x);
  cvt_f32_bf16<<<n4w / 256, 256, 0, stream>>>(wq, Wq, n4w);
  cvt_f32_bf16<<<n4w / 256, 256, 0, stream>>>(wk, Wk, n4w);
  cvt_f32_bf16<<<n4w / 256, 256, 0, stream>>>(wv, Wv, n4w);
  cvt_f32_bf16<<<n4w / 256, 256, 0, stream>>>(wo, Wo, n4w);

  dim3 ggrid(NHH / 128, BT / 128);  // (8, 32)
  gemm_bt<0><<<ggrid, 256, 0, stream>>>(Xq, Wq, Qraw, BT, NHH, EE);
  gemm_bt<0><<<ggrid, 256, 0, stream>>>(Xkv, Wk, Kraw, BT, NHH, EE);
  gemm_bt<1><<<ggrid, 256, 0, stream>>>(Xkv, Wv, Vb, BT, NHH, EE);

  ln_rows<<<BT, 256, 0, stream>>>(Qraw, qs, qb, Qln);
  ln_rows<<<BT, 256, 0, stream>>>(Kraw, kls, klb, Kln);

  transpose_v<<<dim3(TT / 64, BB * HH), 256, 0, stream>>>(Vb, Vt);

  attn_fwd<<<dim3(BB * HH, TT / 64), 256, 0, stream>>>(Qln, Kln, Vt, AOut);

  gemm_bt<0><<<ggrid, 256, 0, stream>>>(AOut, Wo, out, BT, EE, NHH);
}

// Round 2
// 285.481 us; speedup vs baseline: 1.1201x; 1.1201x over previous
//
#include <hip/hip_runtime.h>
#include <stdint.h>

// ---- problem constants ----
#define BB 2
#define TT 2048
#define EE 1024
#define HH 16
#define DD 64
#define NHH 1024
#define BT 4096  // BB*TT
#define NT 32    // q tiles of 64
#define PSTR 136 // P row stride (elems)

typedef unsigned short u16_t;
typedef __bf16 bf16_t;
typedef bf16_t bf16x8 __attribute__((ext_vector_type(8)));
typedef float f32x4 __attribute__((ext_vector_type(4)));

__device__ __forceinline__ u16_t f2bf(float f) {
  union { float f; uint32_t u; } v; v.f = f;
  return (u16_t)((v.u + 0x7fffu + ((v.u >> 16) & 1u)) >> 16);
}

__device__ __forceinline__ void gl_lds16(const u16_t* g, u16_t* l) {
  __builtin_amdgcn_global_load_lds(
      (const __attribute__((address_space(1))) uint32_t*)g,
      (__attribute__((address_space(3))) uint32_t*)l, 16, 0, 0);
}

// ---- fp32 -> bf16 convert (vectorized) ----
__global__ __launch_bounds__(256) void cvt_f32_bf16(const float* __restrict__ in,
                                                    u16_t* __restrict__ out, int n4) {
  int i = blockIdx.x * 256 + threadIdx.x;
  if (i < n4) {
    float4 v = ((const float4*)in)[i];
    ushort4 o;
    o.x = f2bf(v.x); o.y = f2bf(v.y); o.z = f2bf(v.z); o.w = f2bf(v.w);
    ((ushort4*)out)[i] = o;
  }
}

// ---- fused QKV GEMM: N=3072 bands (Q|K|V), 128x128 tile, bf16 out ----
__global__ __launch_bounds__(256, 2) void gemm_qkv(const u16_t* __restrict__ Xq,
                                                   const u16_t* __restrict__ Xkv,
                                                   const u16_t* __restrict__ Wqkv,
                                                   u16_t* __restrict__ Qpre,
                                                   u16_t* __restrict__ Kpre,
                                                   u16_t* __restrict__ Vb) {
  __shared__ __align__(16) u16_t As[128 * 64];
  __shared__ __align__(16) u16_t Bs[128 * 64];
  const int tid = threadIdx.x;
  const int lane = tid & 63;
  const int w = tid >> 6;
  const int wm = w >> 1, wn = w & 1;
  const int nt = blockIdx.x, mt = blockIdx.y;
  const int l15 = lane & 15, l4 = lane >> 4;
  const int band = nt >> 3;
  const u16_t* A = (band == 0) ? Xq : Xkv;
  u16_t* C = (band == 0) ? Qpre : (band == 1) ? Kpre : Vb;
  const int ncol0 = (nt & 7) * 128;

  f32x4 acc[4][4] = {};
  for (int ks = 0; ks < 16; ++ks) {
    const int k0 = ks << 6;
#pragma unroll
    for (int i = 0; i < 4; ++i) {
      int ci = i * 256 + w * 64 + lane;
      int row = ci >> 3, c8 = ci & 7;
      int c8s = c8 ^ (row & 7);
      gl_lds16(A + (size_t)(mt * 128 + row) * EE + k0 + c8s * 8,
               &As[(i * 256 + w * 64) * 8]);
      gl_lds16(Wqkv + (size_t)(nt * 128 + row) * EE + k0 + c8s * 8,
               &Bs[(i * 256 + w * 64) * 8]);
    }
    __syncthreads();
#pragma unroll
    for (int kt = 0; kt < 2; ++kt) {
      bf16x8 af[4], bfr[4];
#pragma unroll
      for (int m = 0; m < 4; ++m) {
        int r = wm * 64 + m * 16 + l15;
        af[m] = *(const bf16x8*)&As[r * 64 + ((kt * 4 + l4) ^ (r & 7)) * 8];
      }
#pragma unroll
      for (int n = 0; n < 4; ++n) {
        int r = wn * 64 + n * 16 + l15;
        bfr[n] = *(const bf16x8*)&Bs[r * 64 + ((kt * 4 + l4) ^ (r & 7)) * 8];
      }
#pragma unroll
      for (int m = 0; m < 4; ++m)
#pragma unroll
        for (int n = 0; n < 4; ++n)
          acc[m][n] = __builtin_amdgcn_mfma_f32_16x16x32_bf16(af[m], bfr[n], acc[m][n], 0, 0, 0);
    }
    __syncthreads();
  }
#pragma unroll
  for (int m = 0; m < 4; ++m)
#pragma unroll
    for (int n = 0; n < 4; ++n)
#pragma unroll
      for (int r = 0; r < 4; ++r) {
        int row = mt * 128 + wm * 64 + m * 16 + l4 * 4 + r;
        int col = ncol0 + wn * 64 + n * 16 + l15;
        C[(size_t)row * NHH + col] = f2bf(acc[m][n][r]);
      }
}

// ---- Wo GEMM: 64x128 tile, fp32 out. C[m][n] = sum_k A[m][k]*W[n][k] ----
__global__ __launch_bounds__(256, 2) void gemm_out(const u16_t* __restrict__ A,
                                                   const u16_t* __restrict__ W,
                                                   float* __restrict__ C) {
  __shared__ __align__(16) u16_t As[64 * 64];
  __shared__ __align__(16) u16_t Bs[128 * 64];
  const int tid = threadIdx.x;
  const int lane = tid & 63;
  const int w = tid >> 6;
  const int wm = w >> 1, wn = w & 1;
  const int nt = blockIdx.x, mt = blockIdx.y;
  const int l15 = lane & 15, l4 = lane >> 4;

  f32x4 acc[2][4] = {};
  for (int ks = 0; ks < 16; ++ks) {
    const int k0 = ks << 6;
#pragma unroll
    for (int i = 0; i < 6; ++i) {
      int ci = i * 256 + w * 64 + lane;
      if (i < 2) {
        int row = ci >> 3, c8s = (ci & 7) ^ ((ci >> 3) & 7);
        gl_lds16(A + (size_t)(mt * 64 + row) * NHH + k0 + c8s * 8,
                 &As[(i * 256 + w * 64) * 8]);
      } else {
        int cj = ci - 512;
        int row = cj >> 3, c8s = (cj & 7) ^ ((cj >> 3) & 7);
        gl_lds16(W + (size_t)(nt * 128 + row) * NHH + k0 + c8s * 8,
                 &Bs[(i * 256 + w * 64 - 512) * 8]);
      }
    }
    __syncthreads();
#pragma unroll
    for (int kt = 0; kt < 2; ++kt) {
      bf16x8 af[2], bfr[4];
#pragma unroll
      for (int m = 0; m < 2; ++m) {
        int r = wm * 32 + m * 16 + l15;
        af[m] = *(const bf16x8*)&As[r * 64 + ((kt * 4 + l4) ^ (r & 7)) * 8];
      }
#pragma unroll
      for (int n = 0; n < 4; ++n) {
        int r = wn * 64 + n * 16 + l15;
        bfr[n] = *(const bf16x8*)&Bs[r * 64 + ((kt * 4 + l4) ^ (r & 7)) * 8];
      }
#pragma unroll
      for (int m = 0; m < 2; ++m)
#pragma unroll
        for (int n = 0; n < 4; ++n)
          acc[m][n] = __builtin_amdgcn_mfma_f32_16x16x32_bf16(af[m], bfr[n], acc[m][n], 0, 0, 0);
    }
    __syncthreads();
  }
#pragma unroll
  for (int m = 0; m < 2; ++m)
#pragma unroll
    for (int n = 0; n < 4; ++n)
#pragma unroll
      for (int r = 0; r < 4; ++r) {
        int row = mt * 64 + wm * 32 + m * 16 + l4 * 4 + r;
        int col = nt * 128 + wn * 64 + n * 16 + l15;
        C[(size_t)row * NHH + col] = acc[m][n][r];
      }
}

// ---- row LayerNorm over NH=1024, bf16 in -> bf16 out ----
__global__ __launch_bounds__(256) void ln_rows_bf16(const u16_t* __restrict__ X,
                                                    const float* __restrict__ scale,
                                                    const float* __restrict__ bias,
                                                    u16_t* __restrict__ Y) {
  int row = blockIdx.x;
  int tid = threadIdx.x;
  ushort4 v4 = ((const ushort4*)(X + (size_t)row * NHH))[tid];
  float x[4];
  {
    union { uint32_t u; float f; } c;
    c.u = (uint32_t)v4.x << 16; x[0] = c.f;
    c.u = (uint32_t)v4.y << 16; x[1] = c.f;
    c.u = (uint32_t)v4.z << 16; x[2] = c.f;
    c.u = (uint32_t)v4.w << 16; x[3] = c.f;
  }
  float s = x[0] + x[1] + x[2] + x[3];
  float sq = x[0] * x[0] + x[1] * x[1] + x[2] * x[2] + x[3] * x[3];
#pragma unroll
  for (int m = 1; m < 64; m <<= 1) {
    s += __shfl_xor(s, m);
    sq += __shfl_xor(sq, m);
  }
  __shared__ float ss[4], ssq[4];
  int w = tid >> 6;
  if ((tid & 63) == 0) { ss[w] = s; ssq[w] = sq; }
  __syncthreads();
  s = ss[0] + ss[1] + ss[2] + ss[3];
  sq = ssq[0] + ssq[1] + ssq[2] + ssq[3];
  float mean = s * (1.0f / 1024.0f);
  float var = sq * (1.0f / 1024.0f) - mean * mean;
  float rstd = rsqrtf(var + 1e-5f);
  float4 sc = ((const float4*)scale)[tid];
  float4 bi = ((const float4*)bias)[tid];
  ushort4 o;
  o.x = f2bf((x[0] - mean) * rstd * sc.x + bi.x);
  o.y = f2bf((x[1] - mean) * rstd * sc.y + bi.y);
  o.z = f2bf((x[2] - mean) * rstd * sc.z + bi.z);
  o.w = f2bf((x[3] - mean) * rstd * sc.w + bi.w);
  ((ushort4*)Y)[(size_t)row * 256 + tid] = o;
}

// ---- V [BT, NH] -> Vt [B,H,D,T] ----
__global__ __launch_bounds__(256) void transpose_v(const u16_t* __restrict__ V,
                                                   u16_t* __restrict__ Vt) {
  __shared__ u16_t tile[64][72];
  int tt = blockIdx.x, bh = blockIdx.y;
  int b = bh >> 4, h = bh & 15;
  int tid = threadIdx.x;
#pragma unroll
  for (int i = 0; i < 4; ++i) {
    int idx = i * 256 + tid;
    int t = idx >> 4, c4 = idx & 15;
    ushort4 v = *(const ushort4*)&V[(size_t)(b * TT + tt * 64 + t) * NHH + h * 64 + c4 * 4];
    *(ushort4*)&tile[t][c4 * 4] = v;
  }
  __syncthreads();
#pragma unroll
  for (int i = 0; i < 4; ++i) {
    int idx = i * 256 + tid;
    int d = idx >> 4, c4 = idx & 15;
    ushort4 o;
    o.x = tile[c4 * 4 + 0][d];
    o.y = tile[c4 * 4 + 1][d];
    o.z = tile[c4 * 4 + 2][d];
    o.w = tile[c4 * 4 + 3][d];
    *(ushort4*)&Vt[((size_t)bh * 64 + d) * TT + tt * 64 + c4 * 4] = o;
  }
}

// ---- causal flash attention, paired q-tiles, KVBLK=128, per-wave causal skip ----
// grid (bh=32, pair=16); block: 4 waves, each owns 16 q-rows of the 64-row q-tile.
__global__ __launch_bounds__(256, 2) void attn_fwd(const u16_t* __restrict__ Q,
                                                   const u16_t* __restrict__ K,
                                                   const u16_t* __restrict__ Vt,
                                                   u16_t* __restrict__ O) {
  __shared__ __align__(16) u16_t Ks[128 * 64];
  __shared__ __align__(16) u16_t Vs[64 * 128];
  __shared__ __align__(16) u16_t Ps[4][16 * PSTR];
  const int bh = blockIdx.x, pr = blockIdx.y;
  const int b = bh >> 4, h = bh & 15;
  const int tid = threadIdx.x, lane = tid & 63, w = tid >> 6;
  const int l15 = lane & 15, l4 = lane >> 4;
  const float SCALE = 0.125f * 1.44269504f;  // 1/sqrt(D) * log2(e)
  u16_t* pw = &Ps[w][0];

  for (int half = 0; half < 2; ++half) {
    const int qt = half ? (NT - 1 - pr) : pr;
    const int q0 = qt * 64 + w * 16;  // wave's first q row

    bf16x8 qf[2];
#pragma unroll
    for (int kt = 0; kt < 2; ++kt)
      qf[kt] = *(const bf16x8*)&Q[(size_t)(b * TT + q0 + l15) * NHH +
                                  h * 64 + kt * 32 + l4 * 8];

    f32x4 accO[4] = {};
    float mrow[4], lrow[4];
#pragma unroll
    for (int r = 0; r < 4; ++r) { mrow[r] = -1e30f; lrow[r] = 0.f; }

    const int nkv = (qt * 64 + 191) >> 7;
    for (int j = 0; j < nkv; ++j) {
      const int kb = j << 7;
      // stage K [128 kv][64 d] and Vt [64 d][128 kv], source-side XOR swizzle
#pragma unroll
      for (int i = 0; i < 4; ++i) {
        int ci = i * 256 + w * 64 + lane;
        int rowk = ci >> 3, c8s = (ci & 7) ^ (rowk & 7);
        gl_lds16(K + (size_t)(b * TT + kb + rowk) * NHH + h * 64 + c8s * 8,
                 &Ks[(i * 256 + w * 64) * 8]);
        int rowv = ci >> 4, c16s = (ci & 15) ^ (rowv & 15);
        gl_lds16(Vt + ((size_t)bh * 64 + rowv) * TT + kb + c16s * 8,
                 &Vs[(i * 256 + w * 64) * 8]);
      }
      __syncthreads();

      const int ktlim = min(4, max(1, (q0 + 15 - kb) / 32 + 1));
      const int nact = ktlim * 2;
      const bool domask = (kb + 127 > q0);

      // S = Q K^T over active kv subtiles
      f32x4 s[8];
#pragma unroll
      for (int n = 0; n < 8; ++n) {
        if (n < nact) {
          s[n] = (f32x4){0.f, 0.f, 0.f, 0.f};
#pragma unroll
          for (int kt = 0; kt < 2; ++kt) {
            int r = n * 16 + l15;
            bf16x8 kf = *(const bf16x8*)&Ks[r * 64 + ((kt * 4 + l4) ^ (r & 7)) * 8];
            s[n] = __builtin_amdgcn_mfma_f32_16x16x32_bf16(qf[kt], kf, s[n], 0, 0, 0);
          }
        }
      }
      // scale + causal mask
#pragma unroll
      for (int n = 0; n < 8; ++n) {
        if (n < nact) {
#pragma unroll
          for (int r = 0; r < 4; ++r) {
            float sv = s[n][r] * SCALE;
            if (domask && (kb + n * 16 + l15 > q0 + l4 * 4 + r)) sv = -1e30f;
            s[n][r] = sv;
          }
        }
      }
      // row max
      float tmax[4];
#pragma unroll
      for (int r = 0; r < 4; ++r) tmax[r] = -1e30f;
#pragma unroll
      for (int n = 0; n < 8; ++n)
        if (n < nact)
#pragma unroll
          for (int r = 0; r < 4; ++r) tmax[r] = fmaxf(tmax[r], s[n][r]);
#pragma unroll
      for (int msk = 1; msk < 16; msk <<= 1)
#pragma unroll
        for (int r = 0; r < 4; ++r) tmax[r] = fmaxf(tmax[r], __shfl_xor(tmax[r], msk));
      // defer-max: rescale only if the running max grew
      float g = fmaxf(fmaxf(tmax[0] - mrow[0], tmax[1] - mrow[1]),
                      fmaxf(tmax[2] - mrow[2], tmax[3] - mrow[3]));
      if (__any(g > 0.f)) {
#pragma unroll
        for (int r = 0; r < 4; ++r) {
          float mn = fmaxf(mrow[r], tmax[r]);
          float scl = exp2f(mrow[r] - mn);
          lrow[r] *= scl;
          mrow[r] = mn;
#pragma unroll
          for (int dn = 0; dn < 4; ++dn) accO[dn][r] *= scl;
        }
      }
      // exp + row sum
      float tsum[4];
#pragma unroll
      for (int r = 0; r < 4; ++r) tsum[r] = 0.f;
#pragma unroll
      for (int n = 0; n < 8; ++n)
        if (n < nact)
#pragma unroll
          for (int r = 0; r < 4; ++r) {
            float p = exp2f(s[n][r] - mrow[r]);
            s[n][r] = p;
            tsum[r] += p;
          }
#pragma unroll
      for (int msk = 1; msk < 16; msk <<= 1)
#pragma unroll
        for (int r = 0; r < 4; ++r) tsum[r] += __shfl_xor(tsum[r], msk);
#pragma unroll
      for (int r = 0; r < 4; ++r) lrow[r] += tsum[r];

      // P -> per-wave LDS
#pragma unroll
      for (int n = 0; n < 8; ++n)
        if (n < nact)
#pragma unroll
          for (int r = 0; r < 4; ++r)
            pw[(l4 * 4 + r) * PSTR + n * 16 + l15] = f2bf(s[n][r]);
      // PV over active kv halves
#pragma unroll
      for (int kt = 0; kt < 4; ++kt) {
        if (kt < ktlim) {
          bf16x8 pf = *(const bf16x8*)&pw[l15 * PSTR + kt * 32 + l4 * 8];
#pragma unroll
          for (int dn = 0; dn < 4; ++dn) {
            int r = dn * 16 + l15;
            bf16x8 vf = *(const bf16x8*)&Vs[r * 128 + ((kt * 4 + l4) ^ (r & 15)) * 8];
            accO[dn] = __builtin_amdgcn_mfma_f32_16x16x32_bf16(pf, vf, accO[dn], 0, 0, 0);
          }
        }
      }
      __syncthreads();
    }
    // epilogue
    float rinv[4];
#pragma unroll
    for (int r = 0; r < 4; ++r) rinv[r] = 1.0f / lrow[r];
#pragma unroll
    for (int dn = 0; dn < 4; ++dn)
#pragma unroll
      for (int r = 0; r < 4; ++r) {
        int row = b * TT + q0 + l4 * 4 + r;
        int col = h * 64 + dn * 16 + l15;
        O[(size_t)row * NHH + col] = f2bf(accO[dn][r] * rinv[r]);
      }
  }
}

// ---- launch ----
extern "C" void kernel_launch(void* const* d_in, const int* in_sizes, int n_in,
                              void* d_out, int out_size, void* d_ws, size_t ws_size,
                              hipStream_t stream) {
  const float* inq = (const float*)d_in[0];
  const float* inkv = (const float*)d_in[1];
  const float* wq = (const float*)d_in[3];
  const float* wk = (const float*)d_in[4];
  const float* wv = (const float*)d_in[5];
  const float* wo = (const float*)d_in[6];
  const float* qs = (const float*)d_in[7];
  const float* qb = (const float*)d_in[8];
  const float* kls = (const float*)d_in[9];
  const float* klb = (const float*)d_in[10];
  float* out = (float*)d_out;

  uint8_t* ws = (uint8_t*)d_ws;
  const size_t SZ_X = (size_t)BT * NHH * 2;  // 8 MiB bf16
  const size_t SZ_W = (size_t)NHH * EE * 2;  // 2 MiB bf16
  u16_t* Xq   = (u16_t*)(ws);
  u16_t* Xkv  = (u16_t*)(ws + SZ_X);
  u16_t* Wqkv = (u16_t*)(ws + 2 * SZ_X);             // 3 bands
  u16_t* Wo   = (u16_t*)(ws + 2 * SZ_X + 3 * SZ_W);
  u16_t* Qpre = (u16_t*)(ws + 2 * SZ_X + 4 * SZ_W);
  u16_t* Kpre = (u16_t*)(ws + 3 * SZ_X + 4 * SZ_W);
  u16_t* Vb   = (u16_t*)(ws + 4 * SZ_X + 4 * SZ_W);
  u16_t* Qln  = (u16_t*)(ws + 5 * SZ_X + 4 * SZ_W);
  u16_t* Kln  = (u16_t*)(ws + 6 * SZ_X + 4 * SZ_W);
  u16_t* Vt   = (u16_t*)(ws + 7 * SZ_X + 4 * SZ_W);
  u16_t* AOut = (u16_t*)(ws + 8 * SZ_X + 4 * SZ_W);

  const int n4x = BT * NHH / 4;
  const int n4w = NHH * EE / 4;
  cvt_f32_bf16<<<n4x / 256, 256, 0, stream>>>(inq, Xq, n4x);
  cvt_f32_bf16<<<n4x / 256, 256, 0, stream>>>(inkv, Xkv, n4x);
  cvt_f32_bf16<<<n4w / 256, 256, 0, stream>>>(wq, Wqkv, n4w);
  cvt_f32_bf16<<<n4w / 256, 256, 0, stream>>>(wk, Wqkv + (size_t)NHH * EE, n4w);
  cvt_f32_bf16<<<n4w / 256, 256, 0, stream>>>(wv, Wqkv + (size_t)2 * NHH * EE, n4w);
  cvt_f32_bf16<<<n4w / 256, 256, 0, stream>>>(wo, Wo, n4w);

  gemm_qkv<<<dim3(24, 32), 256, 0, stream>>>(Xq, Xkv, Wqkv, Qpre, Kpre, Vb);

  ln_rows_bf16<<<BT, 256, 0, stream>>>(Qpre, qs, qb, Qln);
  ln_rows_bf16<<<BT, 256, 0, stream>>>(Kpre, kls, klb, Kln);

  transpose_v<<<dim3(TT / 64, BB * HH), 256, 0, stream>>>(Vb, Vt);

  attn_fwd<<<dim3(BB * HH, NT / 2), 256, 0, stream>>>(Qln, Kln, Vt, AOut);

  gemm_out<<<dim3(8, 64), 256, 0, stream>>>(AOut, Wo, out);
}

// Round 3
// 237.067 us; speedup vs baseline: 1.3488x; 1.2042x over previous
//
#include <hip/hip_runtime.h>
#include <stdint.h>

// ---- problem constants ----
#define BB 2
#define TT 2048
#define EE 1024
#define HH 16
#define DD 64
#define NHH 1024
#define BT 4096  // BB*TT
#define NT 32    // q tiles of 64

typedef unsigned short u16_t;
typedef __bf16 bf16_t;
typedef bf16_t bf16x8 __attribute__((ext_vector_type(8)));
typedef bf16_t bf16x4 __attribute__((ext_vector_type(4)));
typedef float f32x4 __attribute__((ext_vector_type(4)));

__device__ __forceinline__ u16_t f2bf(float f) {
  union { float f; uint32_t u; } v; v.f = f;
  return (u16_t)((v.u + 0x7fffu + ((v.u >> 16) & 1u)) >> 16);
}

__device__ __forceinline__ uint32_t cvtpk_bf16(float lo, float hi) {
  uint32_t r;
  asm("v_cvt_pk_bf16_f32 %0, %1, %2" : "=v"(r) : "v"(lo), "v"(hi));
  return r;
}

__device__ __forceinline__ void gl_lds16(const u16_t* g, u16_t* l) {
  __builtin_amdgcn_global_load_lds(
      (const __attribute__((address_space(1))) uint32_t*)g,
      (__attribute__((address_space(3))) uint32_t*)l, 16, 0, 0);
}

// ---- all fp32 -> bf16 conversions in one grid-stride kernel ----
__global__ __launch_bounds__(256) void cvt_all(const float* __restrict__ inq,
                                               const float* __restrict__ inkv,
                                               const float* __restrict__ wq,
                                               const float* __restrict__ wk,
                                               const float* __restrict__ wv,
                                               const float* __restrict__ wo,
                                               u16_t* __restrict__ Xq,
                                               u16_t* __restrict__ Xkv,
                                               u16_t* __restrict__ Wqkv,
                                               u16_t* __restrict__ Wo) {
  const int NX = BT * NHH / 4;   // 1048576 float4s
  const int NW = NHH * EE / 4;   // 262144
  const int total = 2 * NX + 4 * NW;
  for (int idx = blockIdx.x * 256 + threadIdx.x; idx < total; idx += gridDim.x * 256) {
    const float* src; u16_t* dst; int off;
    if (idx < NX)            { src = inq;  dst = Xq;  off = idx; }
    else if (idx < 2 * NX)   { src = inkv; dst = Xkv; off = idx - NX; }
    else if (idx < 2 * NX + NW)     { src = wq; dst = Wqkv;                       off = idx - 2 * NX; }
    else if (idx < 2 * NX + 2 * NW) { src = wk; dst = Wqkv + (size_t)NHH * EE;    off = idx - (2 * NX + NW); }
    else if (idx < 2 * NX + 3 * NW) { src = wv; dst = Wqkv + (size_t)2 * NHH * EE; off = idx - (2 * NX + 2 * NW); }
    else                            { src = wo; dst = Wo;                          off = idx - (2 * NX + 3 * NW); }
    float4 v = ((const float4*)src)[off];
    ushort4 o;
    o.x = f2bf(v.x); o.y = f2bf(v.y); o.z = f2bf(v.z); o.w = f2bf(v.w);
    ((ushort4*)dst)[off] = o;
  }
}

// ---- fused QKV GEMM: N=3072 bands (Q|K|V), 128x128 tile, bf16 out ----
__global__ __launch_bounds__(256, 3) void gemm_qkv(const u16_t* __restrict__ Xq,
                                                   const u16_t* __restrict__ Xkv,
                                                   const u16_t* __restrict__ Wqkv,
                                                   u16_t* __restrict__ Qpre,
                                                   u16_t* __restrict__ Kpre,
                                                   u16_t* __restrict__ Vb) {
  __shared__ __align__(16) u16_t As[128 * 64];
  __shared__ __align__(16) u16_t Bs[128 * 64];
  const int tid = threadIdx.x;
  const int lane = tid & 63;
  const int w = tid >> 6;
  const int wm = w >> 1, wn = w & 1;
  const int nt = blockIdx.x, mt = blockIdx.y;
  const int l15 = lane & 15, l4 = lane >> 4;
  const int band = nt >> 3;
  const u16_t* A = (band == 0) ? Xq : Xkv;
  u16_t* C = (band == 0) ? Qpre : (band == 1) ? Kpre : Vb;
  const int ncol0 = (nt & 7) * 128;

  f32x4 acc[4][4] = {};
  for (int ks = 0; ks < 16; ++ks) {
    const int k0 = ks << 6;
#pragma unroll
    for (int i = 0; i < 4; ++i) {
      int ci = i * 256 + w * 64 + lane;
      int row = ci >> 3, c8 = ci & 7;
      int c8s = c8 ^ (row & 7);
      gl_lds16(A + (size_t)(mt * 128 + row) * EE + k0 + c8s * 8,
               &As[(i * 256 + w * 64) * 8]);
      gl_lds16(Wqkv + (size_t)(nt * 128 + row) * EE + k0 + c8s * 8,
               &Bs[(i * 256 + w * 64) * 8]);
    }
    __syncthreads();
#pragma unroll
    for (int kt = 0; kt < 2; ++kt) {
      bf16x8 af[4], bfr[4];
#pragma unroll
      for (int m = 0; m < 4; ++m) {
        int r = wm * 64 + m * 16 + l15;
        af[m] = *(const bf16x8*)&As[r * 64 + ((kt * 4 + l4) ^ (r & 7)) * 8];
      }
#pragma unroll
      for (int n = 0; n < 4; ++n) {
        int r = wn * 64 + n * 16 + l15;
        bfr[n] = *(const bf16x8*)&Bs[r * 64 + ((kt * 4 + l4) ^ (r & 7)) * 8];
      }
#pragma unroll
      for (int m = 0; m < 4; ++m)
#pragma unroll
        for (int n = 0; n < 4; ++n)
          acc[m][n] = __builtin_amdgcn_mfma_f32_16x16x32_bf16(af[m], bfr[n], acc[m][n], 0, 0, 0);
    }
    __syncthreads();
  }
#pragma unroll
  for (int m = 0; m < 4; ++m)
#pragma unroll
    for (int n = 0; n < 4; ++n)
#pragma unroll
      for (int r = 0; r < 4; ++r) {
        int row = mt * 128 + wm * 64 + m * 16 + l4 * 4 + r;
        int col = ncol0 + wn * 64 + n * 16 + l15;
        C[(size_t)row * NHH + col] = f2bf(acc[m][n][r]);
      }
}

// ---- Wo GEMM: 64x128 tile, fp32 out ----
__global__ __launch_bounds__(256, 3) void gemm_out(const u16_t* __restrict__ A,
                                                   const u16_t* __restrict__ W,
                                                   float* __restrict__ C) {
  __shared__ __align__(16) u16_t As[64 * 64];
  __shared__ __align__(16) u16_t Bs[128 * 64];
  const int tid = threadIdx.x;
  const int lane = tid & 63;
  const int w = tid >> 6;
  const int wm = w >> 1, wn = w & 1;
  const int nt = blockIdx.x, mt = blockIdx.y;
  const int l15 = lane & 15, l4 = lane >> 4;

  f32x4 acc[2][4] = {};
  for (int ks = 0; ks < 16; ++ks) {
    const int k0 = ks << 6;
#pragma unroll
    for (int i = 0; i < 6; ++i) {
      int ci = i * 256 + w * 64 + lane;
      if (i < 2) {
        int row = ci >> 3, c8s = (ci & 7) ^ ((ci >> 3) & 7);
        gl_lds16(A + (size_t)(mt * 64 + row) * NHH + k0 + c8s * 8,
                 &As[(i * 256 + w * 64) * 8]);
      } else {
        int cj = ci - 512;
        int row = cj >> 3, c8s = (cj & 7) ^ ((cj >> 3) & 7);
        gl_lds16(W + (size_t)(nt * 128 + row) * NHH + k0 + c8s * 8,
                 &Bs[(i * 256 + w * 64 - 512) * 8]);
      }
    }
    __syncthreads();
#pragma unroll
    for (int kt = 0; kt < 2; ++kt) {
      bf16x8 af[2], bfr[4];
#pragma unroll
      for (int m = 0; m < 2; ++m) {
        int r = wm * 32 + m * 16 + l15;
        af[m] = *(const bf16x8*)&As[r * 64 + ((kt * 4 + l4) ^ (r & 7)) * 8];
      }
#pragma unroll
      for (int n = 0; n < 4; ++n) {
        int r = wn * 64 + n * 16 + l15;
        bfr[n] = *(const bf16x8*)&Bs[r * 64 + ((kt * 4 + l4) ^ (r & 7)) * 8];
      }
#pragma unroll
      for (int m = 0; m < 2; ++m)
#pragma unroll
        for (int n = 0; n < 4; ++n)
          acc[m][n] = __builtin_amdgcn_mfma_f32_16x16x32_bf16(af[m], bfr[n], acc[m][n], 0, 0, 0);
    }
    __syncthreads();
  }
#pragma unroll
  for (int m = 0; m < 2; ++m)
#pragma unroll
    for (int n = 0; n < 4; ++n)
#pragma unroll
      for (int r = 0; r < 4; ++r) {
        int row = mt * 64 + wm * 32 + m * 16 + l4 * 4 + r;
        int col = nt * 128 + wn * 64 + n * 16 + l15;
        C[(size_t)row * NHH + col] = acc[m][n][r];
      }
}

// ---- Q-LN and K-LN in one dispatch (blockIdx.y selects) ----
__global__ __launch_bounds__(256) void ln_both(const u16_t* __restrict__ Qpre,
                                               const u16_t* __restrict__ Kpre,
                                               const float* __restrict__ qs,
                                               const float* __restrict__ qb,
                                               const float* __restrict__ ks,
                                               const float* __restrict__ kb,
                                               u16_t* __restrict__ Qln,
                                               u16_t* __restrict__ Kln) {
  int which = blockIdx.y;
  const u16_t* X = which ? Kpre : Qpre;
  const float* scale = which ? ks : qs;
  const float* bias = which ? kb : qb;
  u16_t* Y = which ? Kln : Qln;
  int row = blockIdx.x;
  int tid = threadIdx.x;
  ushort4 v4 = ((const ushort4*)(X + (size_t)row * NHH))[tid];
  float x[4];
  {
    union { uint32_t u; float f; } c;
    c.u = (uint32_t)v4.x << 16; x[0] = c.f;
    c.u = (uint32_t)v4.y << 16; x[1] = c.f;
    c.u = (uint32_t)v4.z << 16; x[2] = c.f;
    c.u = (uint32_t)v4.w << 16; x[3] = c.f;
  }
  float s = x[0] + x[1] + x[2] + x[3];
  float sq = x[0] * x[0] + x[1] * x[1] + x[2] * x[2] + x[3] * x[3];
#pragma unroll
  for (int m = 1; m < 64; m <<= 1) {
    s += __shfl_xor(s, m);
    sq += __shfl_xor(sq, m);
  }
  __shared__ float ss[4], ssq[4];
  int w = tid >> 6;
  if ((tid & 63) == 0) { ss[w] = s; ssq[w] = sq; }
  __syncthreads();
  s = ss[0] + ss[1] + ss[2] + ss[3];
  sq = ssq[0] + ssq[1] + ssq[2] + ssq[3];
  float mean = s * (1.0f / 1024.0f);
  float var = sq * (1.0f / 1024.0f) - mean * mean;
  float rstd = rsqrtf(var + 1e-5f);
  float4 sc = ((const float4*)scale)[tid];
  float4 bi = ((const float4*)bias)[tid];
  ushort4 o;
  o.x = f2bf((x[0] - mean) * rstd * sc.x + bi.x);
  o.y = f2bf((x[1] - mean) * rstd * sc.y + bi.y);
  o.z = f2bf((x[2] - mean) * rstd * sc.z + bi.z);
  o.w = f2bf((x[3] - mean) * rstd * sc.w + bi.w);
  ((ushort4*)Y)[(size_t)row * 256 + tid] = o;
}

// ---- V [BT, NH] -> Vt [B,H,D,T] ----
__global__ __launch_bounds__(256) void transpose_v(const u16_t* __restrict__ V,
                                                   u16_t* __restrict__ Vt) {
  __shared__ u16_t tile[64][72];
  int tt = blockIdx.x, bh = blockIdx.y;
  int b = bh >> 4, h = bh & 15;
  int tid = threadIdx.x;
#pragma unroll
  for (int i = 0; i < 4; ++i) {
    int idx = i * 256 + tid;
    int t = idx >> 4, c4 = idx & 15;
    ushort4 v = *(const ushort4*)&V[(size_t)(b * TT + tt * 64 + t) * NHH + h * 64 + c4 * 4];
    *(ushort4*)&tile[t][c4 * 4] = v;
  }
  __syncthreads();
#pragma unroll
  for (int i = 0; i < 4; ++i) {
    int idx = i * 256 + tid;
    int d = idx >> 4, c4 = idx & 15;
    ushort4 o;
    o.x = tile[c4 * 4 + 0][d];
    o.y = tile[c4 * 4 + 1][d];
    o.z = tile[c4 * 4 + 2][d];
    o.w = tile[c4 * 4 + 3][d];
    *(ushort4*)&Vt[((size_t)bh * 64 + d) * TT + tt * 64 + c4 * 4] = o;
  }
}

// ---- causal flash attention, swapped-QK (T12), in-register P, KVBLK=128 ----
// grid (bh=32, pair=16); block: 8 waves (512 thr). Waves 0-3 -> heavy q-tile
// (NT-1-pr), waves 4-7 -> light (pr); K/V staging shared. P never touches LDS:
// kv-permutation pi applied to both P (A-frag) and V (B-frag).
__global__ __launch_bounds__(512, 4) void attn_fwd(const u16_t* __restrict__ Q,
                                                   const u16_t* __restrict__ K,
                                                   const u16_t* __restrict__ Vt,
                                                   u16_t* __restrict__ O) {
  __shared__ __align__(16) u16_t Ks[128 * 64];
  __shared__ __align__(16) u16_t Vs[64 * 128];
  const int bh = blockIdx.x, pr = blockIdx.y;
  const int b = bh >> 4, h = bh & 15;
  const int tid = threadIdx.x, lane = tid & 63, w = tid >> 6;
  const int l15 = lane & 15, l4 = lane >> 4;
  const float SCALE = 0.125f * 1.44269504f;  // 1/sqrt(D) * log2(e)

  const int qtH = NT - 1 - pr;
  const int my_qt = (w < 4) ? qtH : pr;
  const int q0 = my_qt * 64 + (w & 3) * 16;  // wave's first q row
  const int myq = q0 + l15;                  // this lane's q row (softmax domain)

  // Q as B-fragment, pre-scaled by SCALE: lane holds Q[myq][kt*32 + l4*8 + i]
  bf16x8 qf[2];
#pragma unroll
  for (int kt = 0; kt < 2; ++kt) {
    bf16x8 t = *(const bf16x8*)&Q[(size_t)(b * TT + myq) * NHH + h * 64 + kt * 32 + l4 * 8];
    union { bf16x8 v; uint32_t u[4]; } tt;
    tt.v = t;
#pragma unroll
    for (int d2 = 0; d2 < 4; ++d2) {
      union { uint32_t u; float f; } lo, hi;
      lo.u = tt.u[d2] << 16;
      hi.u = tt.u[d2] & 0xffff0000u;
      tt.u[d2] = cvtpk_bf16(lo.f * SCALE, hi.f * SCALE);
    }
    qf[kt] = tt.v;
  }

  f32x4 accO[4] = {};
  float mrow = -1e30f, lrow = 0.f;

  const int nkv = (qtH + 2) >> 1;  // kv tiles of 128 covering heavy tile
  for (int j = 0; j < nkv; ++j) {
    const int kb = j << 7;
    // stage K [128 kv][64 d] and Vt [64 d][128 kv], source-side XOR swizzle
#pragma unroll
    for (int i = 0; i < 2; ++i) {
      int ci = i * 512 + tid;
      int rowk = ci >> 3, c8s = (ci & 7) ^ (rowk & 7);
      gl_lds16(K + (size_t)(b * TT + kb + rowk) * NHH + h * 64 + c8s * 8, &Ks[ci * 8]);
      int rowv = ci >> 4, c16s = (ci & 15) ^ (rowv & 15);
      gl_lds16(Vt + ((size_t)bh * 64 + rowv) * TT + kb + c16s * 8, &Vs[ci * 8]);
    }
    __syncthreads();

    if (kb <= q0 + 15) {
      const int rel = q0 + 15 - kb;
      const int nact = min(8, (rel >> 4) + 1);   // active 16-kv subtiles
      const int ktlim = min(4, (rel >> 5) + 1);  // active 32-kv blocks (PV)
      const bool domask = (kb + 127 > q0);

      // S^T = K Q^T : lane holds S[kv = kb + n*16 + l4*4 + r][q = myq]
      f32x4 s[8];
#pragma unroll
      for (int n = 0; n < 8; ++n) {
        if (n < nact) {
          s[n] = (f32x4){0.f, 0.f, 0.f, 0.f};
#pragma unroll
          for (int kt = 0; kt < 2; ++kt) {
            int r = n * 16 + l15;
            bf16x8 kf = *(const bf16x8*)&Ks[r * 64 + ((kt * 4 + l4) ^ (r & 7)) * 8];
            s[n] = __builtin_amdgcn_mfma_f32_16x16x32_bf16(kf, qf[kt], s[n], 0, 0, 0);
          }
        }
      }
      if (domask) {
#pragma unroll
        for (int n = 0; n < 8; ++n)
          if (n < nact)
#pragma unroll
            for (int r = 0; r < 4; ++r)
              if (kb + n * 16 + l4 * 4 + r > myq) s[n][r] = -3e38f;
      }
      // row max: lane-local + 2 shuffles
      float tmax = -3e38f;
#pragma unroll
      for (int n = 0; n < 8; ++n)
        if (n < nact)
#pragma unroll
          for (int r = 0; r < 4; ++r) tmax = fmaxf(tmax, s[n][r]);
      tmax = fmaxf(tmax, __shfl_xor(tmax, 16));
      tmax = fmaxf(tmax, __shfl_xor(tmax, 32));
      // defer-max: rescale only when max grew by > 8 (exp2 domain)
      if (__any(tmax > mrow + 8.f)) {
        float mnew = fmaxf(mrow, tmax);
        float scl = exp2f(mrow - mnew);
        lrow *= scl;
        mrow = mnew;
#pragma unroll
        for (int r = 0; r < 4; ++r) {
          float sr = __shfl(scl, l4 * 4 + r);
#pragma unroll
          for (int dn = 0; dn < 4; ++dn) accO[dn][r] *= sr;
        }
      }
      // exp + row sum
      float tsum = 0.f;
#pragma unroll
      for (int n = 0; n < 8; ++n)
        if (n < nact)
#pragma unroll
          for (int r = 0; r < 4; ++r) {
            float p = exp2f(s[n][r] - mrow);
            s[n][r] = p;
            tsum += p;
          }
      tsum += __shfl_xor(tsum, 16);
      tsum += __shfl_xor(tsum, 32);
      lrow += tsum;
      // zero the pad subtile if nact is odd
#pragma unroll
      for (int n = 0; n < 8; ++n)
        if (n >= nact && n < 2 * ktlim) s[n] = (f32x4){0.f, 0.f, 0.f, 0.f};

      // PV: A = P packed in-register (pi-permuted), B = V via 2x ds_read_b64
#pragma unroll
      for (int kt = 0; kt < 4; ++kt) {
        if (kt < ktlim) {
          union { uint32_t u[4]; bf16x8 v; } pa;
          pa.u[0] = cvtpk_bf16(s[2 * kt][0], s[2 * kt][1]);
          pa.u[1] = cvtpk_bf16(s[2 * kt][2], s[2 * kt][3]);
          pa.u[2] = cvtpk_bf16(s[2 * kt + 1][0], s[2 * kt + 1][1]);
          pa.u[3] = cvtpk_bf16(s[2 * kt + 1][2], s[2 * kt + 1][3]);
#pragma unroll
          for (int dn = 0; dn < 4; ++dn) {
            int drow = dn * 16 + l15;
            int c0 = (kt * 4 + (l4 >> 1)) ^ (drow & 15);
            int c1 = (kt * 4 + 2 + (l4 >> 1)) ^ (drow & 15);
            int sub = (l4 & 1) * 4;
            union { bf16x4 h[2]; bf16x8 v; } vf;
            vf.h[0] = *(const bf16x4*)&Vs[drow * 128 + c0 * 8 + sub];
            vf.h[1] = *(const bf16x4*)&Vs[drow * 128 + c1 * 8 + sub];
            accO[dn] = __builtin_amdgcn_mfma_f32_16x16x32_bf16(pa.v, vf.v, accO[dn], 0, 0, 0);
          }
        }
      }
    }
    __syncthreads();
  }
  // epilogue: accO rows are q0 + l4*4 + r; lrow lives at lane l15 == local q
#pragma unroll
  for (int r = 0; r < 4; ++r) {
    float lr = __shfl(lrow, l4 * 4 + r);
    float rinv = 1.0f / lr;
    int row = b * TT + q0 + l4 * 4 + r;
#pragma unroll
    for (int dn = 0; dn < 4; ++dn)
      O[(size_t)row * NHH + h * 64 + dn * 16 + l15] = f2bf(accO[dn][r] * rinv);
  }
}

// ---- launch ----
extern "C" void kernel_launch(void* const* d_in, const int* in_sizes, int n_in,
                              void* d_out, int out_size, void* d_ws, size_t ws_size,
                              hipStream_t stream) {
  const float* inq = (const float*)d_in[0];
  const float* inkv = (const float*)d_in[1];
  const float* wq = (const float*)d_in[3];
  const float* wk = (const float*)d_in[4];
  const float* wv = (const float*)d_in[5];
  const float* wo = (const float*)d_in[6];
  const float* qs = (const float*)d_in[7];
  const float* qb = (const float*)d_in[8];
  const float* kls = (const float*)d_in[9];
  const float* klb = (const float*)d_in[10];
  float* out = (float*)d_out;

  uint8_t* ws = (uint8_t*)d_ws;
  const size_t SZ_X = (size_t)BT * NHH * 2;  // 8 MiB bf16
  const size_t SZ_W = (size_t)NHH * EE * 2;  // 2 MiB bf16
  u16_t* Xq   = (u16_t*)(ws);
  u16_t* Xkv  = (u16_t*)(ws + SZ_X);
  u16_t* Wqkv = (u16_t*)(ws + 2 * SZ_X);             // 3 bands
  u16_t* Wo   = (u16_t*)(ws + 2 * SZ_X + 3 * SZ_W);
  u16_t* Qpre = (u16_t*)(ws + 2 * SZ_X + 4 * SZ_W);
  u16_t* Kpre = (u16_t*)(ws + 3 * SZ_X + 4 * SZ_W);
  u16_t* Vb   = (u16_t*)(ws + 4 * SZ_X + 4 * SZ_W);
  u16_t* Qln  = (u16_t*)(ws + 5 * SZ_X + 4 * SZ_W);
  u16_t* Kln  = (u16_t*)(ws + 6 * SZ_X + 4 * SZ_W);
  u16_t* Vt   = (u16_t*)(ws + 7 * SZ_X + 4 * SZ_W);
  u16_t* AOut = (u16_t*)(ws + 8 * SZ_X + 4 * SZ_W);

  cvt_all<<<3072, 256, 0, stream>>>(inq, inkv, wq, wk, wv, wo, Xq, Xkv, Wqkv, Wo);

  gemm_qkv<<<dim3(24, 32), 256, 0, stream>>>(Xq, Xkv, Wqkv, Qpre, Kpre, Vb);

  ln_both<<<dim3(BT, 2), 256, 0, stream>>>(Qpre, Kpre, qs, qb, kls, klb, Qln, Kln);

  transpose_v<<<dim3(TT / 64, BB * HH), 256, 0, stream>>>(Vb, Vt);

  attn_fwd<<<dim3(BB * HH, NT / 2), 512, 0, stream>>>(Qln, Kln, Vt, AOut);

  gemm_out<<<dim3(8, 64), 256, 0, stream>>>(AOut, Wo, out);
}

// Round 4
// 236.140 us; speedup vs baseline: 1.3541x; 1.0039x over previous
//
#include <hip/hip_runtime.h>
#include <stdint.h>

// ---- problem constants ----
#define BB 2
#define TT 2048
#define EE 1024
#define HH 16
#define DD 64
#define NHH 1024
#define BT 4096  // BB*TT
#define NT 32    // q tiles of 64

typedef unsigned short u16_t;
typedef __bf16 bf16_t;
typedef bf16_t bf16x8 __attribute__((ext_vector_type(8)));
typedef bf16_t bf16x4 __attribute__((ext_vector_type(4)));
typedef float f32x4 __attribute__((ext_vector_type(4)));

__device__ __forceinline__ u16_t f2bf(float f) {
  union { float f; uint32_t u; } v; v.f = f;
  return (u16_t)((v.u + 0x7fffu + ((v.u >> 16) & 1u)) >> 16);
}

__device__ __forceinline__ uint32_t cvtpk_bf16(float lo, float hi) {
  uint32_t r;
  asm("v_cvt_pk_bf16_f32 %0, %1, %2" : "=v"(r) : "v"(lo), "v"(hi));
  return r;
}

__device__ __forceinline__ void gl_lds16(const u16_t* g, u16_t* l) {
  __builtin_amdgcn_global_load_lds(
      (const __attribute__((address_space(1))) uint32_t*)g,
      (__attribute__((address_space(3))) uint32_t*)l, 16, 0, 0);
}

// ---- all fp32 -> bf16 conversions in one grid-stride kernel ----
__global__ __launch_bounds__(256) void cvt_all(const float* __restrict__ inq,
                                               const float* __restrict__ inkv,
                                               const float* __restrict__ wq,
                                               const float* __restrict__ wk,
                                               const float* __restrict__ wv,
                                               const float* __restrict__ wo,
                                               u16_t* __restrict__ Xq,
                                               u16_t* __restrict__ Xkv,
                                               u16_t* __restrict__ Wqkv,
                                               u16_t* __restrict__ Wo) {
  const int NX = BT * NHH / 4;   // 1048576 float4s
  const int NW = NHH * EE / 4;   // 262144
  const int total = 2 * NX + 4 * NW;
  for (int idx = blockIdx.x * 256 + threadIdx.x; idx < total; idx += gridDim.x * 256) {
    const float* src; u16_t* dst; int off;
    if (idx < NX)            { src = inq;  dst = Xq;  off = idx; }
    else if (idx < 2 * NX)   { src = inkv; dst = Xkv; off = idx - NX; }
    else if (idx < 2 * NX + NW)     { src = wq; dst = Wqkv;                       off = idx - 2 * NX; }
    else if (idx < 2 * NX + 2 * NW) { src = wk; dst = Wqkv + (size_t)NHH * EE;    off = idx - (2 * NX + NW); }
    else if (idx < 2 * NX + 3 * NW) { src = wv; dst = Wqkv + (size_t)2 * NHH * EE; off = idx - (2 * NX + 2 * NW); }
    else                            { src = wo; dst = Wo;                          off = idx - (2 * NX + 3 * NW); }
    float4 v = ((const float4*)src)[off];
    ushort4 o;
    o.x = f2bf(v.x); o.y = f2bf(v.y); o.z = f2bf(v.z); o.w = f2bf(v.w);
    ((ushort4*)dst)[off] = o;
  }
}

// ---- fused QKV GEMM: N=3072 bands (Q|K|V), 128x128 tile, bf16 out ----
__global__ __launch_bounds__(256, 3) void gemm_qkv(const u16_t* __restrict__ Xq,
                                                   const u16_t* __restrict__ Xkv,
                                                   const u16_t* __restrict__ Wqkv,
                                                   u16_t* __restrict__ Qpre,
                                                   u16_t* __restrict__ Kpre,
                                                   u16_t* __restrict__ Vb) {
  __shared__ __align__(16) u16_t As[128 * 64];
  __shared__ __align__(16) u16_t Bs[128 * 64];
  const int tid = threadIdx.x;
  const int lane = tid & 63;
  const int w = tid >> 6;
  const int wm = w >> 1, wn = w & 1;
  const int nt = blockIdx.x, mt = blockIdx.y;
  const int l15 = lane & 15, l4 = lane >> 4;
  const int band = nt >> 3;
  const u16_t* A = (band == 0) ? Xq : Xkv;
  u16_t* C = (band == 0) ? Qpre : (band == 1) ? Kpre : Vb;
  const int ncol0 = (nt & 7) * 128;

  f32x4 acc[4][4] = {};
  for (int ks = 0; ks < 16; ++ks) {
    const int k0 = ks << 6;
#pragma unroll
    for (int i = 0; i < 4; ++i) {
      int ci = i * 256 + w * 64 + lane;
      int row = ci >> 3, c8 = ci & 7;
      int c8s = c8 ^ (row & 7);
      gl_lds16(A + (size_t)(mt * 128 + row) * EE + k0 + c8s * 8,
               &As[(i * 256 + w * 64) * 8]);
      gl_lds16(Wqkv + (size_t)(nt * 128 + row) * EE + k0 + c8s * 8,
               &Bs[(i * 256 + w * 64) * 8]);
    }
    __syncthreads();
#pragma unroll
    for (int kt = 0; kt < 2; ++kt) {
      bf16x8 af[4], bfr[4];
#pragma unroll
      for (int m = 0; m < 4; ++m) {
        int r = wm * 64 + m * 16 + l15;
        af[m] = *(const bf16x8*)&As[r * 64 + ((kt * 4 + l4) ^ (r & 7)) * 8];
      }
#pragma unroll
      for (int n = 0; n < 4; ++n) {
        int r = wn * 64 + n * 16 + l15;
        bfr[n] = *(const bf16x8*)&Bs[r * 64 + ((kt * 4 + l4) ^ (r & 7)) * 8];
      }
#pragma unroll
      for (int m = 0; m < 4; ++m)
#pragma unroll
        for (int n = 0; n < 4; ++n)
          acc[m][n] = __builtin_amdgcn_mfma_f32_16x16x32_bf16(af[m], bfr[n], acc[m][n], 0, 0, 0);
    }
    __syncthreads();
  }
#pragma unroll
  for (int m = 0; m < 4; ++m)
#pragma unroll
    for (int n = 0; n < 4; ++n)
#pragma unroll
      for (int r = 0; r < 4; ++r) {
        int row = mt * 128 + wm * 64 + m * 16 + l4 * 4 + r;
        int col = ncol0 + wn * 64 + n * 16 + l15;
        C[(size_t)row * NHH + col] = f2bf(acc[m][n][r]);
      }
}

// ---- Wo GEMM: 64x128 tile, fp32 out ----
__global__ __launch_bounds__(256, 3) void gemm_out(const u16_t* __restrict__ A,
                                                   const u16_t* __restrict__ W,
                                                   float* __restrict__ C) {
  __shared__ __align__(16) u16_t As[64 * 64];
  __shared__ __align__(16) u16_t Bs[128 * 64];
  const int tid = threadIdx.x;
  const int lane = tid & 63;
  const int w = tid >> 6;
  const int wm = w >> 1, wn = w & 1;
  const int nt = blockIdx.x, mt = blockIdx.y;
  const int l15 = lane & 15, l4 = lane >> 4;

  f32x4 acc[2][4] = {};
  for (int ks = 0; ks < 16; ++ks) {
    const int k0 = ks << 6;
#pragma unroll
    for (int i = 0; i < 6; ++i) {
      int ci = i * 256 + w * 64 + lane;
      if (i < 2) {
        int row = ci >> 3, c8s = (ci & 7) ^ ((ci >> 3) & 7);
        gl_lds16(A + (size_t)(mt * 64 + row) * NHH + k0 + c8s * 8,
                 &As[(i * 256 + w * 64) * 8]);
      } else {
        int cj = ci - 512;
        int row = cj >> 3, c8s = (cj & 7) ^ ((cj >> 3) & 7);
        gl_lds16(W + (size_t)(nt * 128 + row) * NHH + k0 + c8s * 8,
                 &Bs[(i * 256 + w * 64 - 512) * 8]);
      }
    }
    __syncthreads();
#pragma unroll
    for (int kt = 0; kt < 2; ++kt) {
      bf16x8 af[2], bfr[4];
#pragma unroll
      for (int m = 0; m < 2; ++m) {
        int r = wm * 32 + m * 16 + l15;
        af[m] = *(const bf16x8*)&As[r * 64 + ((kt * 4 + l4) ^ (r & 7)) * 8];
      }
#pragma unroll
      for (int n = 0; n < 4; ++n) {
        int r = wn * 64 + n * 16 + l15;
        bfr[n] = *(const bf16x8*)&Bs[r * 64 + ((kt * 4 + l4) ^ (r & 7)) * 8];
      }
#pragma unroll
      for (int m = 0; m < 2; ++m)
#pragma unroll
        for (int n = 0; n < 4; ++n)
          acc[m][n] = __builtin_amdgcn_mfma_f32_16x16x32_bf16(af[m], bfr[n], acc[m][n], 0, 0, 0);
    }
    __syncthreads();
  }
#pragma unroll
  for (int m = 0; m < 2; ++m)
#pragma unroll
    for (int n = 0; n < 4; ++n)
#pragma unroll
      for (int r = 0; r < 4; ++r) {
        int row = mt * 64 + wm * 32 + m * 16 + l4 * 4 + r;
        int col = nt * 128 + wn * 64 + n * 16 + l15;
        C[(size_t)row * NHH + col] = acc[m][n][r];
      }
}

// ---- Q-LN and K-LN in one dispatch (blockIdx.y selects) ----
__global__ __launch_bounds__(256) void ln_both(const u16_t* __restrict__ Qpre,
                                               const u16_t* __restrict__ Kpre,
                                               const float* __restrict__ qs,
                                               const float* __restrict__ qb,
                                               const float* __restrict__ ks,
                                               const float* __restrict__ kb,
                                               u16_t* __restrict__ Qln,
                                               u16_t* __restrict__ Kln) {
  int which = blockIdx.y;
  const u16_t* X = which ? Kpre : Qpre;
  const float* scale = which ? ks : qs;
  const float* bias = which ? kb : qb;
  u16_t* Y = which ? Kln : Qln;
  int row = blockIdx.x;
  int tid = threadIdx.x;
  ushort4 v4 = ((const ushort4*)(X + (size_t)row * NHH))[tid];
  float x[4];
  {
    union { uint32_t u; float f; } c;
    c.u = (uint32_t)v4.x << 16; x[0] = c.f;
    c.u = (uint32_t)v4.y << 16; x[1] = c.f;
    c.u = (uint32_t)v4.z << 16; x[2] = c.f;
    c.u = (uint32_t)v4.w << 16; x[3] = c.f;
  }
  float s = x[0] + x[1] + x[2] + x[3];
  float sq = x[0] * x[0] + x[1] * x[1] + x[2] * x[2] + x[3] * x[3];
#pragma unroll
  for (int m = 1; m < 64; m <<= 1) {
    s += __shfl_xor(s, m);
    sq += __shfl_xor(sq, m);
  }
  __shared__ float ss[4], ssq[4];
  int w = tid >> 6;
  if ((tid & 63) == 0) { ss[w] = s; ssq[w] = sq; }
  __syncthreads();
  s = ss[0] + ss[1] + ss[2] + ss[3];
  sq = ssq[0] + ssq[1] + ssq[2] + ssq[3];
  float mean = s * (1.0f / 1024.0f);
  float var = sq * (1.0f / 1024.0f) - mean * mean;
  float rstd = rsqrtf(var + 1e-5f);
  float4 sc = ((const float4*)scale)[tid];
  float4 bi = ((const float4*)bias)[tid];
  ushort4 o;
  o.x = f2bf((x[0] - mean) * rstd * sc.x + bi.x);
  o.y = f2bf((x[1] - mean) * rstd * sc.y + bi.y);
  o.z = f2bf((x[2] - mean) * rstd * sc.z + bi.z);
  o.w = f2bf((x[3] - mean) * rstd * sc.w + bi.w);
  ((ushort4*)Y)[(size_t)row * 256 + tid] = o;
}

// ---- V [BT, NH] -> Vt [B,H,D,T] ----
__global__ __launch_bounds__(256) void transpose_v(const u16_t* __restrict__ V,
                                                   u16_t* __restrict__ Vt) {
  __shared__ u16_t tile[64][72];
  int tt = blockIdx.x, bh = blockIdx.y;
  int b = bh >> 4, h = bh & 15;
  int tid = threadIdx.x;
#pragma unroll
  for (int i = 0; i < 4; ++i) {
    int idx = i * 256 + tid;
    int t = idx >> 4, c4 = idx & 15;
    ushort4 v = *(const ushort4*)&V[(size_t)(b * TT + tt * 64 + t) * NHH + h * 64 + c4 * 4];
    *(ushort4*)&tile[t][c4 * 4] = v;
  }
  __syncthreads();
#pragma unroll
  for (int i = 0; i < 4; ++i) {
    int idx = i * 256 + tid;
    int d = idx >> 4, c4 = idx & 15;
    ushort4 o;
    o.x = tile[c4 * 4 + 0][d];
    o.y = tile[c4 * 4 + 1][d];
    o.z = tile[c4 * 4 + 2][d];
    o.w = tile[c4 * 4 + 3][d];
    *(ushort4*)&Vt[((size_t)bh * 64 + d) * TT + tt * 64 + c4 * 4] = o;
  }
}

// ---- causal flash attention: swapped-QK, in-register P, KVBLK=128,
// double-buffered K/V with stage-ahead + counted vmcnt, granule-swizzled V ----
__global__ __launch_bounds__(512, 4) void attn_fwd(const u16_t* __restrict__ Q,
                                                   const u16_t* __restrict__ K,
                                                   const u16_t* __restrict__ Vt,
                                                   u16_t* __restrict__ O) {
  __shared__ __align__(16) u16_t Ks[2][128 * 64];
  __shared__ __align__(16) u16_t Vs[2][64 * 128];
  const int bh = blockIdx.x, pr = blockIdx.y;
  const int b = bh >> 4, h = bh & 15;
  const int tid = threadIdx.x, lane = tid & 63, w = tid >> 6;
  const int l15 = lane & 15, l4 = lane >> 4;
  const float SCALE = 0.125f * 1.44269504f;  // 1/sqrt(D) * log2(e)

  const int qtH = NT - 1 - pr;
  const int my_qt = (w < 4) ? qtH : pr;
  const int q0 = my_qt * 64 + (w & 3) * 16;  // wave's first q row
  const int myq = q0 + l15;                  // this lane's q row (softmax domain)

  // Q as B-fragment, pre-scaled by SCALE
  bf16x8 qf[2];
#pragma unroll
  for (int kt = 0; kt < 2; ++kt) {
    bf16x8 t = *(const bf16x8*)&Q[(size_t)(b * TT + myq) * NHH + h * 64 + kt * 32 + l4 * 8];
    union { bf16x8 v; uint32_t u[4]; } tt;
    tt.v = t;
#pragma unroll
    for (int d2 = 0; d2 < 4; ++d2) {
      union { uint32_t u; float f; } lo, hi;
      lo.u = tt.u[d2] << 16;
      hi.u = tt.u[d2] & 0xffff0000u;
      tt.u[d2] = cvtpk_bf16(lo.f * SCALE, hi.f * SCALE);
    }
    qf[kt] = tt.v;
  }

  f32x4 accO[4] = {};
  float mrow = -1e30f, lrow = 0.f;

  const int nkv = (qtH + 2) >> 1;  // kv tiles of 128 covering heavy tile

  // stage K tile [128 kv][64 d] (16B-chunk swizzle ^row&7) and
  // Vt tile [64 d][128 kv] (8B-granule swizzle, mask ((row>>1)&7)<<1 -> source
  // 16B chunk ^ ((row>>1)&7), bit0 untouched so the 16B copy stays contiguous)
  auto stage_kv = [&](int j, int bi) {
    const int kb_ = j << 7;
#pragma unroll
    for (int i = 0; i < 2; ++i) {
      int ci = i * 512 + tid;
      int rowk = ci >> 3, c8s = (ci & 7) ^ (rowk & 7);
      gl_lds16(K + (size_t)(b * TT + kb_ + rowk) * NHH + h * 64 + c8s * 8,
               &Ks[bi][ci * 8]);
      int rowv = ci >> 4, c16s = (ci & 15) ^ ((rowv >> 1) & 7);
      gl_lds16(Vt + ((size_t)bh * 64 + rowv) * TT + kb_ + c16s * 8,
               &Vs[bi][ci * 8]);
    }
  };

  stage_kv(0, 0);
  for (int j = 0; j < nkv; ++j) {
    const int kb = j << 7;
    const int bi = j & 1;
    if (j + 1 < nkv) {
      stage_kv(j + 1, bi ^ 1);
      asm volatile("s_waitcnt vmcnt(4)" ::: "memory");  // tile j landed; j+1 in flight
    } else {
      asm volatile("s_waitcnt vmcnt(0)" ::: "memory");
    }
    __builtin_amdgcn_s_barrier();
    __builtin_amdgcn_sched_barrier(0);

    if (kb <= q0 + 15) {
      const int rel = q0 + 15 - kb;
      const int nact = min(8, (rel >> 4) + 1);   // active 16-kv subtiles
      const int ktlim = min(4, (rel >> 5) + 1);  // active 32-kv blocks (PV)
      const bool domask = (kb + 127 > q0);

      // S^T = K Q^T : lane holds S[kv = kb + n*16 + l4*4 + r][q = myq]
      f32x4 s[8];
      __builtin_amdgcn_s_setprio(1);
#pragma unroll
      for (int n = 0; n < 8; ++n) {
        if (n < nact) {
          s[n] = (f32x4){0.f, 0.f, 0.f, 0.f};
#pragma unroll
          for (int kt = 0; kt < 2; ++kt) {
            int r = n * 16 + l15;
            bf16x8 kf = *(const bf16x8*)&Ks[bi][r * 64 + ((kt * 4 + l4) ^ (r & 7)) * 8];
            s[n] = __builtin_amdgcn_mfma_f32_16x16x32_bf16(kf, qf[kt], s[n], 0, 0, 0);
          }
        }
      }
      __builtin_amdgcn_s_setprio(0);
      if (domask) {
#pragma unroll
        for (int n = 0; n < 8; ++n)
          if (n < nact)
#pragma unroll
            for (int r = 0; r < 4; ++r)
              if (kb + n * 16 + l4 * 4 + r > myq) s[n][r] = -3e38f;
      }
      // row max: lane-local + 2 shuffles
      float tmax = -3e38f;
#pragma unroll
      for (int n = 0; n < 8; ++n)
        if (n < nact)
#pragma unroll
          for (int r = 0; r < 4; ++r) tmax = fmaxf(tmax, s[n][r]);
      tmax = fmaxf(tmax, __shfl_xor(tmax, 16));
      tmax = fmaxf(tmax, __shfl_xor(tmax, 32));
      // defer-max: rescale only when max grew by > 8 (exp2 domain)
      if (__any(tmax > mrow + 8.f)) {
        float mnew = fmaxf(mrow, tmax);
        float scl = exp2f(mrow - mnew);
        lrow *= scl;
        mrow = mnew;
#pragma unroll
        for (int r = 0; r < 4; ++r) {
          float sr = __shfl(scl, l4 * 4 + r);
#pragma unroll
          for (int dn = 0; dn < 4; ++dn) accO[dn][r] *= sr;
        }
      }
      // exp + row sum
      float tsum = 0.f;
#pragma unroll
      for (int n = 0; n < 8; ++n)
        if (n < nact)
#pragma unroll
          for (int r = 0; r < 4; ++r) {
            float p = exp2f(s[n][r] - mrow);
            s[n][r] = p;
            tsum += p;
          }
      tsum += __shfl_xor(tsum, 16);
      tsum += __shfl_xor(tsum, 32);
      lrow += tsum;
      // zero the pad subtile if nact is odd
#pragma unroll
      for (int n = 0; n < 8; ++n)
        if (n >= nact && n < 2 * ktlim) s[n] = (f32x4){0.f, 0.f, 0.f, 0.f};

      // PV: A = P packed in-register, B = V via 2x conflict-free ds_read_b64
      __builtin_amdgcn_s_setprio(1);
#pragma unroll
      for (int kt = 0; kt < 4; ++kt) {
        if (kt < ktlim) {
          union { uint32_t u[4]; bf16x8 v; } pa;
          pa.u[0] = cvtpk_bf16(s[2 * kt][0], s[2 * kt][1]);
          pa.u[1] = cvtpk_bf16(s[2 * kt][2], s[2 * kt][3]);
          pa.u[2] = cvtpk_bf16(s[2 * kt + 1][0], s[2 * kt + 1][1]);
          pa.u[3] = cvtpk_bf16(s[2 * kt + 1][2], s[2 * kt + 1][3]);
#pragma unroll
          for (int dn = 0; dn < 4; ++dn) {
            int drow = dn * 16 + l15;
            int vm = ((drow >> 1) & 7) << 1;
            int pg0 = (kt * 8 + l4) ^ vm;
            int pg1 = (kt * 8 + 4 + l4) ^ vm;
            union { bf16x4 h[2]; bf16x8 v; } vf;
            vf.h[0] = *(const bf16x4*)&Vs[bi][drow * 128 + pg0 * 4];
            vf.h[1] = *(const bf16x4*)&Vs[bi][drow * 128 + pg1 * 4];
            accO[dn] = __builtin_amdgcn_mfma_f32_16x16x32_bf16(pa.v, vf.v, accO[dn], 0, 0, 0);
          }
        }
      }
      __builtin_amdgcn_s_setprio(0);
    }
    __builtin_amdgcn_sched_barrier(0);
    __builtin_amdgcn_s_barrier();
  }
  // epilogue: accO rows are q0 + l4*4 + r; lrow lives at lane l15 == local q
#pragma unroll
  for (int r = 0; r < 4; ++r) {
    float lr = __shfl(lrow, l4 * 4 + r);
    float rinv = 1.0f / lr;
    int row = b * TT + q0 + l4 * 4 + r;
#pragma unroll
    for (int dn = 0; dn < 4; ++dn)
      O[(size_t)row * NHH + h * 64 + dn * 16 + l15] = f2bf(accO[dn][r] * rinv);
  }
}

// ---- launch ----
extern "C" void kernel_launch(void* const* d_in, const int* in_sizes, int n_in,
                              void* d_out, int out_size, void* d_ws, size_t ws_size,
                              hipStream_t stream) {
  const float* inq = (const float*)d_in[0];
  const float* inkv = (const float*)d_in[1];
  const float* wq = (const float*)d_in[3];
  const float* wk = (const float*)d_in[4];
  const float* wv = (const float*)d_in[5];
  const float* wo = (const float*)d_in[6];
  const float* qs = (const float*)d_in[7];
  const float* qb = (const float*)d_in[8];
  const float* kls = (const float*)d_in[9];
  const float* klb = (const float*)d_in[10];
  float* out = (float*)d_out;

  uint8_t* ws = (uint8_t*)d_ws;
  const size_t SZ_X = (size_t)BT * NHH * 2;  // 8 MiB bf16
  const size_t SZ_W = (size_t)NHH * EE * 2;  // 2 MiB bf16
  u16_t* Xq   = (u16_t*)(ws);
  u16_t* Xkv  = (u16_t*)(ws + SZ_X);
  u16_t* Wqkv = (u16_t*)(ws + 2 * SZ_X);             // 3 bands
  u16_t* Wo   = (u16_t*)(ws + 2 * SZ_X + 3 * SZ_W);
  u16_t* Qpre = (u16_t*)(ws + 2 * SZ_X + 4 * SZ_W);
  u16_t* Kpre = (u16_t*)(ws + 3 * SZ_X + 4 * SZ_W);
  u16_t* Vb   = (u16_t*)(ws + 4 * SZ_X + 4 * SZ_W);
  u16_t* Qln  = (u16_t*)(ws + 5 * SZ_X + 4 * SZ_W);
  u16_t* Kln  = (u16_t*)(ws + 6 * SZ_X + 4 * SZ_W);
  u16_t* Vt   = (u16_t*)(ws + 7 * SZ_X + 4 * SZ_W);
  u16_t* AOut = (u16_t*)(ws + 8 * SZ_X + 4 * SZ_W);

  cvt_all<<<3072, 256, 0, stream>>>(inq, inkv, wq, wk, wv, wo, Xq, Xkv, Wqkv, Wo);

  gemm_qkv<<<dim3(24, 32), 256, 0, stream>>>(Xq, Xkv, Wqkv, Qpre, Kpre, Vb);

  ln_both<<<dim3(BT, 2), 256, 0, stream>>>(Qpre, Kpre, qs, qb, kls, klb, Qln, Kln);

  transpose_v<<<dim3(TT / 64, BB * HH), 256, 0, stream>>>(Vb, Vt);

  attn_fwd<<<dim3(BB * HH, NT / 2), 512, 0, stream>>>(Qln, Kln, Vt, AOut);

  gemm_out<<<dim3(8, 64), 256, 0, stream>>>(AOut, Wo, out);
}

// Round 7
// 229.912 us; speedup vs baseline: 1.3908x; 1.0271x over previous
//
#include <hip/hip_runtime.h>
#include <stdint.h>

// ---- problem constants ----
#define BB 2
#define TT 2048
#define EE 1024
#define HH 16
#define DD 64
#define NHH 1024
#define BT 4096  // BB*TT
#define NT 32    // q tiles of 64

typedef unsigned short u16_t;
typedef __bf16 bf16_t;
typedef bf16_t bf16x8 __attribute__((ext_vector_type(8)));
typedef bf16_t bf16x4 __attribute__((ext_vector_type(4)));
typedef float f32x4 __attribute__((ext_vector_type(4)));

__device__ __forceinline__ u16_t f2bf(float f) {
  union { float f; uint32_t u; } v; v.f = f;
  return (u16_t)((v.u + 0x7fffu + ((v.u >> 16) & 1u)) >> 16);
}

__device__ __forceinline__ uint32_t cvtpk_bf16(float lo, float hi) {
  uint32_t r;
  asm("v_cvt_pk_bf16_f32 %0, %1, %2" : "=v"(r) : "v"(lo), "v"(hi));
  return r;
}

__device__ __forceinline__ void gl_lds16(const u16_t* g, u16_t* l) {
  __builtin_amdgcn_global_load_lds(
      (const __attribute__((address_space(1))) uint32_t*)g,
      (__attribute__((address_space(3))) uint32_t*)l, 16, 0, 0);
}

// ---- all fp32 -> bf16 conversions in one grid-stride kernel ----
__global__ __launch_bounds__(256) void cvt_all(const float* __restrict__ inq,
                                               const float* __restrict__ inkv,
                                               const float* __restrict__ wq,
                                               const float* __restrict__ wk,
                                               const float* __restrict__ wv,
                                               const float* __restrict__ wo,
                                               u16_t* __restrict__ Xq,
                                               u16_t* __restrict__ Xkv,
                                               u16_t* __restrict__ Wqkv,
                                               u16_t* __restrict__ Wo) {
  const int NX = BT * NHH / 4;   // 1048576 float4s
  const int NW = NHH * EE / 4;   // 262144
  const int total = 2 * NX + 4 * NW;
  for (int idx = blockIdx.x * 256 + threadIdx.x; idx < total; idx += gridDim.x * 256) {
    const float* src; u16_t* dst; int off;
    if (idx < NX)            { src = inq;  dst = Xq;  off = idx; }
    else if (idx < 2 * NX)   { src = inkv; dst = Xkv; off = idx - NX; }
    else if (idx < 2 * NX + NW)     { src = wq; dst = Wqkv;                       off = idx - 2 * NX; }
    else if (idx < 2 * NX + 2 * NW) { src = wk; dst = Wqkv + (size_t)NHH * EE;    off = idx - (2 * NX + NW); }
    else if (idx < 2 * NX + 3 * NW) { src = wv; dst = Wqkv + (size_t)2 * NHH * EE; off = idx - (2 * NX + 2 * NW); }
    else                            { src = wo; dst = Wo;                          off = idx - (2 * NX + 3 * NW); }
    float4 v = ((const float4*)src)[off];
    ushort4 o;
    o.x = f2bf(v.x); o.y = f2bf(v.y); o.z = f2bf(v.z); o.w = f2bf(v.w);
    ((ushort4*)dst)[off] = o;
  }
}

// ---- fused QKV GEMM: N=3072 bands (Q|K|V), 128x128 tile, bf16 out ----
__global__ __launch_bounds__(256, 3) void gemm_qkv(const u16_t* __restrict__ Xq,
                                                   const u16_t* __restrict__ Xkv,
                                                   const u16_t* __restrict__ Wqkv,
                                                   u16_t* __restrict__ Qpre,
                                                   u16_t* __restrict__ Kpre,
                                                   u16_t* __restrict__ Vb) {
  __shared__ __align__(16) u16_t As[128 * 64];
  __shared__ __align__(16) u16_t Bs[128 * 64];
  const int tid = threadIdx.x;
  const int lane = tid & 63;
  const int w = tid >> 6;
  const int wm = w >> 1, wn = w & 1;
  const int nt = blockIdx.x, mt = blockIdx.y;
  const int l15 = lane & 15, l4 = lane >> 4;
  const int band = nt >> 3;
  const u16_t* A = (band == 0) ? Xq : Xkv;
  u16_t* C = (band == 0) ? Qpre : (band == 1) ? Kpre : Vb;
  const int ncol0 = (nt & 7) * 128;

  f32x4 acc[4][4] = {};
  for (int ks = 0; ks < 16; ++ks) {
    const int k0 = ks << 6;
#pragma unroll
    for (int i = 0; i < 4; ++i) {
      int ci = i * 256 + w * 64 + lane;
      int row = ci >> 3, c8 = ci & 7;
      int c8s = c8 ^ (row & 7);
      gl_lds16(A + (size_t)(mt * 128 + row) * EE + k0 + c8s * 8,
               &As[(i * 256 + w * 64) * 8]);
      gl_lds16(Wqkv + (size_t)(nt * 128 + row) * EE + k0 + c8s * 8,
               &Bs[(i * 256 + w * 64) * 8]);
    }
    __syncthreads();
#pragma unroll
    for (int kt = 0; kt < 2; ++kt) {
      bf16x8 af[4], bfr[4];
#pragma unroll
      for (int m = 0; m < 4; ++m) {
        int r = wm * 64 + m * 16 + l15;
        af[m] = *(const bf16x8*)&As[r * 64 + ((kt * 4 + l4) ^ (r & 7)) * 8];
      }
#pragma unroll
      for (int n = 0; n < 4; ++n) {
        int r = wn * 64 + n * 16 + l15;
        bfr[n] = *(const bf16x8*)&Bs[r * 64 + ((kt * 4 + l4) ^ (r & 7)) * 8];
      }
#pragma unroll
      for (int m = 0; m < 4; ++m)
#pragma unroll
        for (int n = 0; n < 4; ++n)
          acc[m][n] = __builtin_amdgcn_mfma_f32_16x16x32_bf16(af[m], bfr[n], acc[m][n], 0, 0, 0);
    }
    __syncthreads();
  }
#pragma unroll
  for (int m = 0; m < 4; ++m)
#pragma unroll
    for (int n = 0; n < 4; ++n)
#pragma unroll
      for (int r = 0; r < 4; ++r) {
        int row = mt * 128 + wm * 64 + m * 16 + l4 * 4 + r;
        int col = ncol0 + wn * 64 + n * 16 + l15;
        C[(size_t)row * NHH + col] = f2bf(acc[m][n][r]);
      }
}

// ---- Wo GEMM: 64x128 tile, fp32 out ----
__global__ __launch_bounds__(256, 3) void gemm_out(const u16_t* __restrict__ A,
                                                   const u16_t* __restrict__ W,
                                                   float* __restrict__ C) {
  __shared__ __align__(16) u16_t As[64 * 64];
  __shared__ __align__(16) u16_t Bs[128 * 64];
  const int tid = threadIdx.x;
  const int lane = tid & 63;
  const int w = tid >> 6;
  const int wm = w >> 1, wn = w & 1;
  const int nt = blockIdx.x, mt = blockIdx.y;
  const int l15 = lane & 15, l4 = lane >> 4;

  f32x4 acc[2][4] = {};
  for (int ks = 0; ks < 16; ++ks) {
    const int k0 = ks << 6;
#pragma unroll
    for (int i = 0; i < 6; ++i) {
      int ci = i * 256 + w * 64 + lane;
      if (i < 2) {
        int row = ci >> 3, c8s = (ci & 7) ^ ((ci >> 3) & 7);
        gl_lds16(A + (size_t)(mt * 64 + row) * NHH + k0 + c8s * 8,
                 &As[(i * 256 + w * 64) * 8]);
      } else {
        int cj = ci - 512;
        int row = cj >> 3, c8s = (cj & 7) ^ ((cj >> 3) & 7);
        gl_lds16(W + (size_t)(nt * 128 + row) * NHH + k0 + c8s * 8,
                 &Bs[(i * 256 + w * 64 - 512) * 8]);
      }
    }
    __syncthreads();
#pragma unroll
    for (int kt = 0; kt < 2; ++kt) {
      bf16x8 af[2], bfr[4];
#pragma unroll
      for (int m = 0; m < 2; ++m) {
        int r = wm * 32 + m * 16 + l15;
        af[m] = *(const bf16x8*)&As[r * 64 + ((kt * 4 + l4) ^ (r & 7)) * 8];
      }
#pragma unroll
      for (int n = 0; n < 4; ++n) {
        int r = wn * 64 + n * 16 + l15;
        bfr[n] = *(const bf16x8*)&Bs[r * 64 + ((kt * 4 + l4) ^ (r & 7)) * 8];
      }
#pragma unroll
      for (int m = 0; m < 2; ++m)
#pragma unroll
        for (int n = 0; n < 4; ++n)
          acc[m][n] = __builtin_amdgcn_mfma_f32_16x16x32_bf16(af[m], bfr[n], acc[m][n], 0, 0, 0);
    }
    __syncthreads();
  }
#pragma unroll
  for (int m = 0; m < 2; ++m)
#pragma unroll
    for (int n = 0; n < 4; ++n)
#pragma unroll
      for (int r = 0; r < 4; ++r) {
        int row = mt * 64 + wm * 32 + m * 16 + l4 * 4 + r;
        int col = nt * 128 + wn * 64 + n * 16 + l15;
        C[(size_t)row * NHH + col] = acc[m][n][r];
      }
}

// ---- Q-LN and K-LN in one dispatch (blockIdx.y selects) ----
__global__ __launch_bounds__(256) void ln_both(const u16_t* __restrict__ Qpre,
                                               const u16_t* __restrict__ Kpre,
                                               const float* __restrict__ qs,
                                               const float* __restrict__ qb,
                                               const float* __restrict__ ks,
                                               const float* __restrict__ kb,
                                               u16_t* __restrict__ Qln,
                                               u16_t* __restrict__ Kln) {
  int which = blockIdx.y;
  const u16_t* X = which ? Kpre : Qpre;
  const float* scale = which ? ks : qs;
  const float* bias = which ? kb : qb;
  u16_t* Y = which ? Kln : Qln;
  int row = blockIdx.x;
  int tid = threadIdx.x;
  ushort4 v4 = ((const ushort4*)(X + (size_t)row * NHH))[tid];
  float x[4];
  {
    union { uint32_t u; float f; } c;
    c.u = (uint32_t)v4.x << 16; x[0] = c.f;
    c.u = (uint32_t)v4.y << 16; x[1] = c.f;
    c.u = (uint32_t)v4.z << 16; x[2] = c.f;
    c.u = (uint32_t)v4.w << 16; x[3] = c.f;
  }
  float s = x[0] + x[1] + x[2] + x[3];
  float sq = x[0] * x[0] + x[1] * x[1] + x[2] * x[2] + x[3] * x[3];
#pragma unroll
  for (int m = 1; m < 64; m <<= 1) {
    s += __shfl_xor(s, m);
    sq += __shfl_xor(sq, m);
  }
  __shared__ float ss[4], ssq[4];
  int w = tid >> 6;
  if ((tid & 63) == 0) { ss[w] = s; ssq[w] = sq; }
  __syncthreads();
  s = ss[0] + ss[1] + ss[2] + ss[3];
  sq = ssq[0] + ssq[1] + ssq[2] + ssq[3];
  float mean = s * (1.0f / 1024.0f);
  float var = sq * (1.0f / 1024.0f) - mean * mean;
  float rstd = rsqrtf(var + 1e-5f);
  float4 sc = ((const float4*)scale)[tid];
  float4 bi = ((const float4*)bias)[tid];
  ushort4 o;
  o.x = f2bf((x[0] - mean) * rstd * sc.x + bi.x);
  o.y = f2bf((x[1] - mean) * rstd * sc.y + bi.y);
  o.z = f2bf((x[2] - mean) * rstd * sc.z + bi.z);
  o.w = f2bf((x[3] - mean) * rstd * sc.w + bi.w);
  ((ushort4*)Y)[(size_t)row * 256 + tid] = o;
}

// ---- V [BT, NH] -> Vt [B,H,D,T] ----
__global__ __launch_bounds__(256) void transpose_v(const u16_t* __restrict__ V,
                                                   u16_t* __restrict__ Vt) {
  __shared__ u16_t tile[64][72];
  int tt = blockIdx.x, bh = blockIdx.y;
  int b = bh >> 4, h = bh & 15;
  int tid = threadIdx.x;
#pragma unroll
  for (int i = 0; i < 4; ++i) {
    int idx = i * 256 + tid;
    int t = idx >> 4, c4 = idx & 15;
    ushort4 v = *(const ushort4*)&V[(size_t)(b * TT + tt * 64 + t) * NHH + h * 64 + c4 * 4];
    *(ushort4*)&tile[t][c4 * 4] = v;
  }
  __syncthreads();
#pragma unroll
  for (int i = 0; i < 4; ++i) {
    int idx = i * 256 + tid;
    int d = idx >> 4, c4 = idx & 15;
    ushort4 o;
    o.x = tile[c4 * 4 + 0][d];
    o.y = tile[c4 * 4 + 1][d];
    o.z = tile[c4 * 4 + 2][d];
    o.w = tile[c4 * 4 + 3][d];
    *(ushort4*)&Vt[((size_t)bh * 64 + d) * TT + tt * 64 + c4 * 4] = o;
  }
}

// ---- causal flash attention: kv-parity split across 8 waves ----
// grid (bh=32, y -> qt descending). Block: 8 waves on ONE 64-row q-tile.
// wave w: q-sub = w&3 (16 rows), kv parity = w>>2 (tiles 2p / 2p+1, KVBLK=64).
// Per-wave partial (m,l,accO); 2-way merge via LDS at the end.
__global__ __launch_bounds__(512, 6) void attn_fwd(const u16_t* __restrict__ Q,
                                                   const u16_t* __restrict__ K,
                                                   const u16_t* __restrict__ Vt,
                                                   u16_t* __restrict__ O) {
  __shared__ __align__(16) u16_t Ks[2][64 * 64];  // [parity][kv][d] chunk-swizzled
  __shared__ __align__(16) u16_t Vs[2][64 * 64];  // [parity][d][kv] granule-swizzled
  const int bh = blockIdx.x;
  const int qt = NT - 1 - (int)blockIdx.y;  // heavy tiles dispatched first
  const int b = bh >> 4, h = bh & 15;
  const int tid = threadIdx.x, lane = tid & 63, w = tid >> 6;
  const int l15 = lane & 15, l4 = lane >> 4;
  const int qsub = w & 3, par = w >> 2;
  const float SCALE = 0.125f * 1.44269504f;  // 1/sqrt(D) * log2(e)

  const int q0 = qt * 64 + qsub * 16;  // wave's first q row
  const int myq = q0 + l15;            // lane's q row (softmax domain)

  // Q as B-fragment, pre-scaled by SCALE
  bf16x8 qf[2];
#pragma unroll
  for (int kt = 0; kt < 2; ++kt) {
    bf16x8 t = *(const bf16x8*)&Q[(size_t)(b * TT + myq) * NHH + h * 64 + kt * 32 + l4 * 8];
    union { bf16x8 v; uint32_t u[4]; } tt;
    tt.v = t;
#pragma unroll
    for (int d2 = 0; d2 < 4; ++d2) {
      union { uint32_t u; float f; } lo, hi;
      lo.u = tt.u[d2] << 16;
      hi.u = tt.u[d2] & 0xffff0000u;
      tt.u[d2] = cvtpk_bf16(lo.f * SCALE, hi.f * SCALE);
    }
    qf[kt] = tt.v;
  }

  // staging pointers (advance by fixed stride per phase)
  const int ci = tid;  // 512 chunks of 16B per 8KB tile
  const int rowk = ci >> 3;
  const int c8k = (ci & 7) ^ (rowk & 7);
  const int c8v = (ci & 7) ^ ((rowk >> 1) & 7);
  const u16_t* kp = K + (size_t)(b * TT + rowk) * NHH + h * 64 + c8k * 8;
  const u16_t* vp = Vt + ((size_t)bh * 64 + rowk) * TT + c8v * 8;
  u16_t* kdst0 = &Ks[0][ci * 8];
  u16_t* kdst1 = &Ks[1][ci * 8];
  u16_t* vdst0 = &Vs[0][ci * 8];
  u16_t* vdst1 = &Vs[1][ci * 8];
  const u16_t* myK = Ks[par];
  const u16_t* myV = Vs[par];

  f32x4 accO[4] = {};
  float mrow = -1e30f, lrow = 0.f;

  const int ntile = qt + 1;          // 64-kv tiles
  const int nph = (ntile + 1) >> 1;  // phases (2 tiles each)

  for (int ph = 0; ph < nph; ++ph) {
    const int t1ok = (2 * ph + 1) < ntile;
    gl_lds16(kp, kdst0);
    gl_lds16(vp, vdst0);
    if (t1ok) {
      gl_lds16(kp + 64 * NHH, kdst1);
      gl_lds16(vp + 64, vdst1);
    }
    kp += 128 * NHH;
    vp += 128;
    __syncthreads();

    const int t = 2 * ph + par;
    if (t < ntile) {
      const int kb = t * 64;
      const bool masked = (t == qt);
      const int nact = masked ? (qsub + 1) : 4;
      const int ktlim = masked ? ((qsub >> 1) + 1) : 2;

      // S^T = K Q^T : lane holds S[kv = kb + n*16 + l4*4 + r][q = myq]
      f32x4 s[4];
      __builtin_amdgcn_s_setprio(1);
#pragma unroll
      for (int n = 0; n < 4; ++n) {
        if (n < nact) {
          s[n] = (f32x4){0.f, 0.f, 0.f, 0.f};
#pragma unroll
          for (int kt = 0; kt < 2; ++kt) {
            int r = n * 16 + l15;
            bf16x8 kf = *(const bf16x8*)&myK[r * 64 + ((kt * 4 + l4) ^ (r & 7)) * 8];
            s[n] = __builtin_amdgcn_mfma_f32_16x16x32_bf16(kf, qf[kt], s[n], 0, 0, 0);
          }
        }
      }
      __builtin_amdgcn_s_setprio(0);
      if (masked) {
#pragma unroll
        for (int n = 0; n < 4; ++n)
          if (n < nact)
#pragma unroll
            for (int r = 0; r < 4; ++r)
              if (kb + n * 16 + l4 * 4 + r > myq) s[n][r] = -3e38f;
      }
      // row max: lane-local + 2 shuffles
      float tmax = -3e38f;
#pragma unroll
      for (int n = 0; n < 4; ++n)
        if (n < nact)
#pragma unroll
          for (int r = 0; r < 4; ++r) tmax = fmaxf(tmax, s[n][r]);
      tmax = fmaxf(tmax, __shfl_xor(tmax, 16));
      tmax = fmaxf(tmax, __shfl_xor(tmax, 32));
      // defer-max: rescale only when max grew by > 8 (exp2 domain)
      if (__any(tmax > mrow + 8.f)) {
        float mnew = fmaxf(mrow, tmax);
        float scl = exp2f(mrow - mnew);
        lrow *= scl;
        mrow = mnew;
#pragma unroll
        for (int r = 0; r < 4; ++r) {
          float sr = __shfl(scl, l4 * 4 + r);
#pragma unroll
          for (int dn = 0; dn < 4; ++dn) accO[dn][r] *= sr;
        }
      }
      // exp + row sum
      float tsum = 0.f;
#pragma unroll
      for (int n = 0; n < 4; ++n)
        if (n < nact)
#pragma unroll
          for (int r = 0; r < 4; ++r) {
            float p = exp2f(s[n][r] - mrow);
            s[n][r] = p;
            tsum += p;
          }
      tsum += __shfl_xor(tsum, 16);
      tsum += __shfl_xor(tsum, 32);
      lrow += tsum;
      // zero pad subtile if nact odd
#pragma unroll
      for (int n = 0; n < 4; ++n)
        if (n >= nact && n < 2 * ktlim) s[n] = (f32x4){0.f, 0.f, 0.f, 0.f};

      // PV: A = P packed in-register, B = V via 2x conflict-free ds_read_b64
      __builtin_amdgcn_s_setprio(1);
#pragma unroll
      for (int kt = 0; kt < 2; ++kt) {
        if (kt < ktlim) {
          union { uint32_t u[4]; bf16x8 v; } pa;
          pa.u[0] = cvtpk_bf16(s[2 * kt][0], s[2 * kt][1]);
          pa.u[1] = cvtpk_bf16(s[2 * kt][2], s[2 * kt][3]);
          pa.u[2] = cvtpk_bf16(s[2 * kt + 1][0], s[2 * kt + 1][1]);
          pa.u[3] = cvtpk_bf16(s[2 * kt + 1][2], s[2 * kt + 1][3]);
#pragma unroll
          for (int dn = 0; dn < 4; ++dn) {
            int drow = dn * 16 + l15;
            int vm = l15 & 14;
            int pg0 = (kt * 8 + l4) ^ vm;
            int pg1 = (kt * 8 + 4 + l4) ^ vm;
            union { bf16x4 hh[2]; bf16x8 v; } vf;
            vf.hh[0] = *(const bf16x4*)&myV[drow * 64 + pg0 * 4];
            vf.hh[1] = *(const bf16x4*)&myV[drow * 64 + pg1 * 4];
            accO[dn] = __builtin_amdgcn_mfma_f32_16x16x32_bf16(pa.v, vf.v, accO[dn], 0, 0, 0);
          }
        }
      }
      __builtin_amdgcn_s_setprio(0);
    }
    __syncthreads();
  }

  // ---- 2-way merge across kv-parity partner waves (LDS overlays Ks/Vs) ----
  float* xch = (float*)&Ks[0][0];
  // layout: [0,5120): par1 accO, stride 20 floats/lane; [5120,5248): par1 m,l;
  // [5248,5376): par0 m,l
  if (par == 1) {
    float* dst = xch + (qsub * 64 + lane) * 20;
#pragma unroll
    for (int dn = 0; dn < 4; ++dn) *(f32x4*)(dst + dn * 4) = accO[dn];
    if (l4 == 0) {
      xch[5120 + qsub * 32 + l15 * 2] = mrow;
      xch[5120 + qsub * 32 + l15 * 2 + 1] = lrow;
    }
  } else {
    if (l4 == 0) {
      xch[5248 + qsub * 32 + l15 * 2] = mrow;
      xch[5248 + qsub * 32 + l15 * 2 + 1] = lrow;
    }
  }
  __syncthreads();
  if (par == 0) {
    const float* src = xch + (qsub * 64 + lane) * 20;
    f32x4 acc1[4];
#pragma unroll
    for (int dn = 0; dn < 4; ++dn) acc1[dn] = *(const f32x4*)(src + dn * 4);
#pragma unroll
    for (int r = 0; r < 4; ++r) {
      int q = l4 * 4 + r;
      float m0 = xch[5248 + qsub * 32 + q * 2];
      float l0 = xch[5248 + qsub * 32 + q * 2 + 1];
      float m1 = xch[5120 + qsub * 32 + q * 2];
      float l1 = xch[5120 + qsub * 32 + q * 2 + 1];
      float mM = fmaxf(m0, m1);
      float s0 = exp2f(m0 - mM), s1 = exp2f(m1 - mM);
      float rinv = 1.0f / (l0 * s0 + l1 * s1);
      int row = b * TT + q0 + q;
#pragma unroll
      for (int dn = 0; dn < 4; ++dn) {
        float o = (accO[dn][r] * s0 + acc1[dn][r] * s1) * rinv;
        O[(size_t)row * NHH + h * 64 + dn * 16 + l15] = f2bf(o);
      }
    }
  }
}

// ---- launch ----
extern "C" void kernel_launch(void* const* d_in, const int* in_sizes, int n_in,
                              void* d_out, int out_size, void* d_ws, size_t ws_size,
                              hipStream_t stream) {
  const float* inq = (const float*)d_in[0];
  const float* inkv = (const float*)d_in[1];
  const float* wq = (const float*)d_in[3];
  const float* wk = (const float*)d_in[4];
  const float* wv = (const float*)d_in[5];
  const float* wo = (const float*)d_in[6];
  const float* qs = (const float*)d_in[7];
  const float* qb = (const float*)d_in[8];
  const float* kls = (const float*)d_in[9];
  const float* klb = (const float*)d_in[10];
  float* out = (float*)d_out;

  uint8_t* ws = (uint8_t*)d_ws;
  const size_t SZ_X = (size_t)BT * NHH * 2;  // 8 MiB bf16
  const size_t SZ_W = (size_t)NHH * EE * 2;  // 2 MiB bf16
  u16_t* Xq   = (u16_t*)(ws);
  u16_t* Xkv  = (u16_t*)(ws + SZ_X);
  u16_t* Wqkv = (u16_t*)(ws + 2 * SZ_X);             // 3 bands
  u16_t* Wo   = (u16_t*)(ws + 2 * SZ_X + 3 * SZ_W);
  u16_t* Qpre = (u16_t*)(ws + 2 * SZ_X + 4 * SZ_W);
  u16_t* Kpre = (u16_t*)(ws + 3 * SZ_X + 4 * SZ_W);
  u16_t* Vb   = (u16_t*)(ws + 4 * SZ_X + 4 * SZ_W);
  u16_t* Qln  = (u16_t*)(ws + 5 * SZ_X + 4 * SZ_W);
  u16_t* Kln  = (u16_t*)(ws + 6 * SZ_X + 4 * SZ_W);
  u16_t* Vt   = (u16_t*)(ws + 7 * SZ_X + 4 * SZ_W);
  u16_t* AOut = (u16_t*)(ws + 8 * SZ_X + 4 * SZ_W);

  cvt_all<<<3072, 256, 0, stream>>>(inq, inkv, wq, wk, wv, wo, Xq, Xkv, Wqkv, Wo);

  gemm_qkv<<<dim3(24, 32), 256, 0, stream>>>(Xq, Xkv, Wqkv, Qpre, Kpre, Vb);

  ln_both<<<dim3(BT, 2), 256, 0, stream>>>(Qpre, Kpre, qs, qb, kls, klb, Qln, Kln);

  transpose_v<<<dim3(TT / 64, BB * HH), 256, 0, stream>>>(Vb, Vt);

  attn_fwd<<<dim3(BB * HH, NT), 512, 0, stream>>>(Qln, Kln, Vt, AOut);

  gemm_out<<<dim3(8, 64), 256, 0, stream>>>(AOut, Wo, out);
}